// Round 8
// baseline (227.217 us; speedup 1.0000x reference)
//
#include <hip/hip_runtime.h>

// Problem constants: b=1, n=4 views, f=8 frames, l=256, C=320, H=8, d=40
#define MROWS 8192   // (b*f) * (n*l)
#define CDIM  320
#define QPAD  512    // padded row stride for Q/K/Qi: 8 heads x 64 (cols 40..63 zero)

typedef __attribute__((ext_vector_type(8))) short bf16x8;
typedef __attribute__((ext_vector_type(4))) float f32x4;

__device__ __forceinline__ unsigned bfbits(float x) {  // round-half-up bf16 bits (hi16)
  union { float f; unsigned u; } a; a.f = x;
  return a.u + 0x8000u;
}
__device__ __forceinline__ unsigned pack2bf(float a, float b) {
  return (bfbits(a) >> 16) | (bfbits(b) & 0xffff0000u);
}
__device__ __forceinline__ void splitbf(float x, short& hi, short& lo) {
  unsigned hu = bfbits(x) & 0xffff0000u;
  union { unsigned u; float f; } h; h.u = hu;
  hi = (short)(hu >> 16);
  lo = (short)(bfbits(x - h.f) >> 16);
}

// rearrange '(b n f) l c -> (b f) (n l) c' row map (involution)
__device__ __forceinline__ int swizzle_row(int r) {
  int ff = r >> 10;
  int t  = r & 1023;
  int nn = t >> 8;
  int ll = t & 255;
  return nn * 2048 + ff * 256 + ll;
}

// ---------------------------------------------------------------------------
// P1: Wc = Wo_i2v @ Wo, fp32, 64x64 tiles, grid (5,5). Tiny (65 MFLOP).
// ---------------------------------------------------------------------------
__global__ __launch_bounds__(256) void wc_kernel(
    const float* __restrict__ Woi, const float* __restrict__ Wo,
    float* __restrict__ Wc)
{
  const int r0 = blockIdx.x * 64, c0 = blockIdx.y * 64;
  __shared__ float As[64][36];
  __shared__ float Bs[32][68];
  const int tid = threadIdx.x, tx = tid & 15, ty = tid >> 4;
  float acc[4][4] = {};

  const int ra = tid >> 3, kq = (tid & 7) * 4;
  const int kb = tid >> 4, cq = (tid & 15) * 4;

  for (int k0 = 0; k0 < 320; k0 += 32) {
    float4 a1 = *(const float4*)(Woi + (size_t)(r0 + ra) * 320 + k0 + kq);
    float4 a2 = *(const float4*)(Woi + (size_t)(r0 + ra + 32) * 320 + k0 + kq);
    float4 b1 = *(const float4*)(Wo + (size_t)(k0 + kb) * 320 + c0 + cq);
    float4 b2 = *(const float4*)(Wo + (size_t)(k0 + kb + 16) * 320 + c0 + cq);
    __syncthreads();
    *(float4*)&As[ra][kq] = a1;
    *(float4*)&As[ra + 32][kq] = a2;
    *(float4*)&Bs[kb][cq] = b1;
    *(float4*)&Bs[kb + 16][cq] = b2;
    __syncthreads();
    #pragma unroll
    for (int kk = 0; kk < 32; ++kk) {
      float4 bv = *(const float4*)&Bs[kk][tx * 4];
      #pragma unroll
      for (int i = 0; i < 4; ++i) {
        float a = As[ty * 4 + i][kk];
        acc[i][0] = fmaf(a, bv.x, acc[i][0]);
        acc[i][1] = fmaf(a, bv.y, acc[i][1]);
        acc[i][2] = fmaf(a, bv.z, acc[i][2]);
        acc[i][3] = fmaf(a, bv.w, acc[i][3]);
      }
    }
  }
  #pragma unroll
  for (int i = 0; i < 4; ++i) {
    float4 v = make_float4(acc[i][0], acc[i][1], acc[i][2], acc[i][3]);
    *(float4*)(Wc + (size_t)(r0 + ty * 4 + i) * 320 + c0 + tx * 4) = v;
  }
}

// ---------------------------------------------------------------------------
// P2: pack/split/zero everything (identical to round 6).
// ---------------------------------------------------------------------------
__global__ __launch_bounds__(256) void pack_kernel(
    const float* __restrict__ hidden,
    const float* __restrict__ Wq, const float* __restrict__ Wk,
    const float* __restrict__ Wv, const float* __restrict__ Wqi,
    const float* __restrict__ Wo, const float* __restrict__ Wc,
    const float* __restrict__ bo, const float* __restrict__ boi,
    short* __restrict__ Ah, short* __restrict__ Al,
    short* __restrict__ WTh, short* __restrict__ WTl,
    short* __restrict__ WFh, short* __restrict__ WFl,
    float* __restrict__ bc,
    short* __restrict__ Qp, short* __restrict__ Kp, short* __restrict__ Qip,
    float qscale)
{
  const int b = blockIdx.x, tid = threadIdx.x;
  if (b < 64) {
    const int r0 = b * 128;
    for (int e = tid; e < 128 * 80; e += 256) {
      int r = e / 80, cq = (e % 80) * 4;
      float4 x = *(const float4*)(hidden + (size_t)swizzle_row(r0 + r) * 320 + cq);
      union { ushort4 v; short s[4]; } h, l;
      splitbf(x.x, h.s[0], l.s[0]); splitbf(x.y, h.s[1], l.s[1]);
      splitbf(x.z, h.s[2], l.s[2]); splitbf(x.w, h.s[3], l.s[3]);
      *(ushort4*)&Ah[(size_t)(r0 + r) * 320 + cq] = h.v;
      *(ushort4*)&Al[(size_t)(r0 + r) * 320 + cq] = l.v;
    }
  } else if (b < 128) {
    const int t2 = b - 64, wi = t2 >> 4, seg = t2 & 15;
    const float* W = wi == 0 ? Wq : wi == 1 ? Wk : wi == 2 ? Wv : Wqi;
    const float s = (wi == 0 || wi == 3) ? qscale : 1.0f;
    short* th = WTh + (size_t)wi * 320 * 320;
    short* tl = WTl + (size_t)wi * 320 * 320;
    for (int e = tid; e < 20 * 320; e += 256) {
      int n = seg * 20 + e / 320, k = e % 320;
      short hi, lo;
      splitbf(W[(size_t)k * 320 + n] * s, hi, lo);
      th[(size_t)n * 320 + k] = hi;
      tl[(size_t)n * 320 + k] = lo;
    }
  } else if (b < 160) {
    const int t2 = b - 128;
    for (int e = tid; e < 10 * 640; e += 256) {
      int n = t2 * 10 + e / 640, k = e % 640;
      float x = (k < 320) ? Wo[(size_t)k * 320 + n] : Wc[(size_t)(k - 320) * 320 + n];
      short hi, lo;
      splitbf(x, hi, lo);
      WFh[(size_t)n * 640 + k] = hi;
      WFl[(size_t)n * 640 + k] = lo;
    }
  } else if (b < 168) {
    const int n = (b - 160) * 40 + tid;
    if (tid < 40) {
      float s = bo[n];
      for (int j = 0; j < 320; ++j) s = fmaf(boi[j], Wo[(size_t)j * 320 + n], s);
      bc[n] = s;
    }
  } else {
    const int bz = b - 168, buf = bz >> 5, seg = bz & 31;
    short* P = buf == 0 ? Qp : buf == 1 ? Kp : Qip;
    const uint4 z = make_uint4(0, 0, 0, 0);
    for (int e = tid; e < 256 * 24; e += 256) {
      int row = (seg << 8) + (e / 24);
      int cc = e % 24, h = cc / 3, c3 = cc % 3;
      *(uint4*)&P[(size_t)row * QPAD + h * 64 + 40 + c3 * 8] = z;
    }
  }
}

// ---------------------------------------------------------------------------
// Split-bf16 MFMA GEMM (identical to round 6).
// ---------------------------------------------------------------------------
__global__ __launch_bounds__(256, 3) void mfma_gemm(
    const short* __restrict__ Ah, const short* __restrict__ Al,
    const short* __restrict__ BTh, const short* __restrict__ BTl,
    int K, int mode,
    short* __restrict__ Qp, short* __restrict__ Kp,
    short* __restrict__ Vt, short* __restrict__ Qip,
    float* __restrict__ Of, const float* __restrict__ bias)
{
  const int tid  = threadIdx.x;
  const int wave = tid >> 6;
  const int lane = tid & 63;
  const int quad = lane >> 4;
  const int l16  = lane & 15;
  const int row0 = blockIdx.x * 128;

  const short *bth, *btl;
  int nbase, wi = 0;
  if (mode == 0) {
    const int ct = blockIdx.y;
    wi = ct / 5;
    bth = BTh + (size_t)wi * 320 * 320;
    btl = BTl + (size_t)wi * 320 * 320;
    nbase = (ct % 5) * 64;
  } else {
    bth = BTh; btl = BTl;
    nbase = blockIdx.y * 64;
  }

  __shared__ short Ash[128][40], Asl[128][40];
  __shared__ short Bsh[64][40],  Bsl[64][40];

  f32x4 acc[2][4];
  #pragma unroll
  for (int mt = 0; mt < 2; ++mt)
    #pragma unroll
    for (int nt = 0; nt < 4; ++nt) acc[mt][nt] = (f32x4){0.f, 0.f, 0.f, 0.f};

  const int ar = tid >> 2, akc = (tid & 3) * 8;
  const int bn = tid >> 2, bkc = (tid & 3) * 8;

  const short* pa_h = Ah + (size_t)(row0 + ar) * K + akc;
  const short* pa_l = Al ? Al + (size_t)(row0 + ar) * K + akc : nullptr;
  const short* pb_h = bth + (size_t)(nbase + bn) * K + bkc;
  const short* pb_l = btl + (size_t)(nbase + bn) * K + bkc;

  for (int k0 = 0; k0 < K; k0 += 32) {
    uint4 ah1 = *(const uint4*)(pa_h + k0);
    uint4 ah2 = *(const uint4*)(pa_h + (size_t)64 * K + k0);
    uint4 al1, al2;
    if (Al) {
      al1 = *(const uint4*)(pa_l + k0);
      al2 = *(const uint4*)(pa_l + (size_t)64 * K + k0);
    }
    uint4 bh = *(const uint4*)(pb_h + k0);
    uint4 bl = *(const uint4*)(pb_l + k0);
    __syncthreads();
    *(uint4*)&Ash[ar][akc]      = ah1;
    *(uint4*)&Ash[ar + 64][akc] = ah2;
    if (Al) {
      *(uint4*)&Asl[ar][akc]      = al1;
      *(uint4*)&Asl[ar + 64][akc] = al2;
    }
    *(uint4*)&Bsh[bn][bkc] = bh;
    *(uint4*)&Bsl[bn][bkc] = bl;
    __syncthreads();

    bf16x8 afh[2], afl[2], bfh[4], bfl[4];
    #pragma unroll
    for (int mt = 0; mt < 2; ++mt) {
      afh[mt] = *(const bf16x8*)&Ash[wave * 32 + mt * 16 + l16][quad * 8];
      if (Al) afl[mt] = *(const bf16x8*)&Asl[wave * 32 + mt * 16 + l16][quad * 8];
    }
    #pragma unroll
    for (int nt = 0; nt < 4; ++nt) {
      bfh[nt] = *(const bf16x8*)&Bsh[nt * 16 + l16][quad * 8];
      bfl[nt] = *(const bf16x8*)&Bsl[nt * 16 + l16][quad * 8];
    }
    #pragma unroll
    for (int mt = 0; mt < 2; ++mt)
      #pragma unroll
      for (int nt = 0; nt < 4; ++nt) {
        acc[mt][nt] = __builtin_amdgcn_mfma_f32_16x16x32_bf16(afh[mt], bfh[nt], acc[mt][nt], 0, 0, 0);
        acc[mt][nt] = __builtin_amdgcn_mfma_f32_16x16x32_bf16(afh[mt], bfl[nt], acc[mt][nt], 0, 0, 0);
        if (Al)
          acc[mt][nt] = __builtin_amdgcn_mfma_f32_16x16x32_bf16(afl[mt], bfh[nt], acc[mt][nt], 0, 0, 0);
      }
  }

  if (mode == 0) {
    if (wi == 2) {
      #pragma unroll
      for (int mt = 0; mt < 2; ++mt)
        #pragma unroll
        for (int nt = 0; nt < 4; ++nt) {
          const int col  = nbase + nt * 16 + l16;
          const int rowb = row0 + wave * 32 + mt * 16 + quad * 4;
          union { ushort4 v; short s[4]; } pk;
          #pragma unroll
          for (int r = 0; r < 4; ++r) pk.s[r] = (short)(bfbits(acc[mt][nt][r]) >> 16);
          *(ushort4*)&Vt[(size_t)col * MROWS + rowb] = pk.v;
        }
    } else {
      short* Op = wi == 0 ? Qp : wi == 1 ? Kp : Qip;
      #pragma unroll
      for (int mt = 0; mt < 2; ++mt)
        #pragma unroll
        for (int nt = 0; nt < 4; ++nt) {
          const int col  = nbase + nt * 16 + l16;
          const int h    = col / 40;
          const int pcol = h * 64 + (col - h * 40);
          const int rowb = row0 + wave * 32 + mt * 16 + quad * 4;
          #pragma unroll
          for (int r = 0; r < 4; ++r)
            Op[(size_t)(rowb + r) * QPAD + pcol] = (short)(bfbits(acc[mt][nt][r]) >> 16);
        }
    }
  } else {
    #pragma unroll
    for (int mt = 0; mt < 2; ++mt)
      #pragma unroll
      for (int nt = 0; nt < 4; ++nt) {
        const int col  = nbase + nt * 16 + l16;
        const int rowb = row0 + wave * 32 + mt * 16 + quad * 4;
        const float bb = bias[col];
        #pragma unroll
        for (int r = 0; r < 4; ++r)
          Of[(size_t)swizzle_row(rowb + r) * CDIM + col] = acc[mt][nt][r] + bb;
      }
  }
}

// ---------------------------------------------------------------------------
// Flash attention, bf16 MFMA, static-max softmax. Round-4 topology (4 waves,
// 32 q-rows/wave, 64-key LDS steps, kt*16+l16 key map) with:
//  - register DOUBLE-BUFFER: next step's staging loads issued right after
//    barrier #2, latency overlaps current step's compute (loads in flight
//    across the barrier). Last-iter prefetch is OOB-safe (lands in adjacent
//    ws buffers, never used).
//  - b64 P stores at [l16][kt*16+quad*4] (uniform 4 words/bank).
//  - numerics identical to round 6 (passed): __expf, pack2bf, qscale=1/sqrt(40).
// grid = (8 qblk, 8 heads, 16 = bf + 8*variant).
// ---------------------------------------------------------------------------
__global__ __launch_bounds__(256, 4) void attn_kernel(
    const short* __restrict__ Qp, const short* __restrict__ Qip,
    const short* __restrict__ Kp, const short* __restrict__ Vtg,
    short* __restrict__ AOh)
{
  const int qblk = blockIdx.x;   // 0..7 (128 q-rows per block)
  const int hh   = blockIdx.y;   // 0..7
  const int zz   = blockIdx.z;   // 0..15
  const int var  = zz >> 3;
  const int bf   = zz & 7;
  const int tid  = threadIdx.x;
  const int wave = tid >> 6;
  const int lane = tid & 63;
  const int quad = lane >> 4;
  const int l16  = lane & 15;

  const short* Q = var ? Qip : Qp;
  const int kvbase = var ? 0 : (bf << 10);
  const int coff = var * 320 + hh * 40;

  __shared__ short Ks[64][72];       // [key][kd], cols 40..71 zero
  __shared__ short Vt[48][72];       // [dcol][key], rows 40..47 zero
  __shared__ short Ps[4][2][16][72]; // per-wave, per-qtile P buffer

  // zero pad regions once (staging never writes them)
  *(uint4*)&Ks[tid >> 2][40 + (tid & 3) * 8] = make_uint4(0, 0, 0, 0);
  if (tid < 64)
    *(uint4*)&Vt[40 + (tid >> 3)][(tid & 7) * 8] = make_uint4(0, 0, 0, 0);

  // Q B-fragments: 2 q-tiles of 16 rows; n = l16 = q-row, k = quad*8+j
  bf16x8 qf0[2], qf1[2];
  #pragma unroll
  for (int qt = 0; qt < 2; ++qt) {
    const short* qp = Q + (size_t)((bf << 10) + (qblk << 7) + (wave << 5) + (qt << 4) + l16) * QPAD + hh * 64;
    qf0[qt] = *(const bf16x8*)(qp + quad * 8);
    qf1[qt] = *(const bf16x8*)(qp + 32 + quad * 8);
  }

  f32x4 acc[2][3];
  float lsum[2] = {0.f, 0.f};
  #pragma unroll
  for (int qt = 0; qt < 2; ++qt)
    #pragma unroll
    for (int t = 0; t < 3; ++t) acc[qt][t] = (f32x4){0.f, 0.f, 0.f, 0.f};

  const short* Kb = Kp + (size_t)kvbase * QPAD + hh * 64;
  const short* Vb = Vtg + (size_t)(hh * 40) * MROWS + kvbase;

  // ---- staging pointers, hoisted (roles wave-uniform) ----
  // p1: all threads -> K units 0..255 (key=tid/5, c=tid%5)
  // p2: wave0 -> K units 256..319; waves1-3 -> V units 0..191
  // p3: waves0-1 -> V units 192..319; waves2-3 idle
  const int k1 = tid / 5, c1 = tid % 5;
  const short* g1 = Kb + (size_t)k1 * QPAD + c1 * 8;
  short*       s1 = &Ks[k1][c1 * 8];
  const short* g2; short* s2; int inc2;
  if (tid < 64) {
    int u = tid + 256, k2 = u / 5, c2 = u % 5;
    g2 = Kb + (size_t)k2 * QPAD + c2 * 8;
    s2 = &Ks[k2][c2 * 8];
    inc2 = 64 * QPAD;
  } else {
    int v = tid - 64;
    g2 = Vb + (size_t)(v >> 3) * MROWS + (v & 7) * 8;
    s2 = &Vt[v >> 3][(v & 7) * 8];
    inc2 = 64;
  }
  const short* g3 = nullptr; short* s3 = nullptr;
  if (tid < 128) {
    int v = tid + 192;
    g3 = Vb + (size_t)(v >> 3) * MROWS + (v & 7) * 8;
    s3 = &Vt[v >> 3][(v & 7) * 8];
  }

  // initial prefetch (step 0)
  uint4 r1 = *(const uint4*)g1;
  uint4 r2 = *(const uint4*)g2;
  uint4 r3 = make_uint4(0, 0, 0, 0);
  if (tid < 128) r3 = *(const uint4*)g3;

  for (int step = 0; step < 16; ++step) {
    __syncthreads();                 // previous step fully consumed
    *(uint4*)s1 = r1;
    *(uint4*)s2 = r2;
    if (tid < 128) *(uint4*)s3 = r3;
    __syncthreads();                 // staging visible

    // ---- issue next step's loads NOW; latency overlaps this step's compute.
    // Last-iter reads are OOB of this KV slice but stay inside d_ws (safe,
    // unused).
    g1 += (size_t)64 * QPAD;
    g2 += inc2;
    r1 = *(const uint4*)g1;
    r2 = *(const uint4*)g2;
    if (tid < 128) { g3 += 64; r3 = *(const uint4*)g3; }

    // V B-fragments (load early; hide under QK MFMAs)
    bf16x8 vf[2][3];
    #pragma unroll
    for (int kh = 0; kh < 2; ++kh)
      #pragma unroll
      for (int t = 0; t < 3; ++t)
        vf[kh][t] = *(const bf16x8*)&Vt[t * 16 + l16][kh * 32 + quad * 8];

    // ---- QK^T + exp + pack, per kt (K frags transient) ----
    #pragma unroll
    for (int kt = 0; kt < 4; ++kt) {
      const short* kr = &Ks[kt * 16 + l16][quad * 8];
      bf16x8 kb0 = *(const bf16x8*)kr;
      bf16x8 kb1 = *(const bf16x8*)(kr + 32);
      #pragma unroll
      for (int qt = 0; qt < 2; ++qt) {
        f32x4 st = (f32x4){0.f, 0.f, 0.f, 0.f};
        st = __builtin_amdgcn_mfma_f32_16x16x32_bf16(kb0, qf0[qt], st, 0, 0, 0);
        st = __builtin_amdgcn_mfma_f32_16x16x32_bf16(kb1, qf1[qt], st, 0, 0, 0);
        float p0 = __expf(st[0]);
        float p1 = __expf(st[1]);
        float p2 = __expf(st[2]);
        float p3 = __expf(st[3]);
        lsum[qt] += (p0 + p1) + (p2 + p3);
        uint2 pk;
        pk.x = pack2bf(p0, p1);
        pk.y = pack2bf(p2, p3);
        // keys kt*16 + quad*4 + {0..3} for q-row l16
        *(uint2*)&Ps[wave][qt][l16][kt * 16 + quad * 4] = pk;
      }
    }

    // wave-internal LDS RAW (cross-lane): drain before reading P
    asm volatile("s_waitcnt lgkmcnt(0)" ::: "memory");

    // ---- P @ V ----
    #pragma unroll
    for (int qt = 0; qt < 2; ++qt) {
      bf16x8 pa0 = *(const bf16x8*)&Ps[wave][qt][l16][quad * 8];
      bf16x8 pa1 = *(const bf16x8*)&Ps[wave][qt][l16][32 + quad * 8];
      #pragma unroll
      for (int t = 0; t < 3; ++t) {
        acc[qt][t] = __builtin_amdgcn_mfma_f32_16x16x32_bf16(pa0, vf[0][t], acc[qt][t], 0, 0, 0);
        acc[qt][t] = __builtin_amdgcn_mfma_f32_16x16x32_bf16(pa1, vf[1][t], acc[qt][t], 0, 0, 0);
      }
    }
  }

  // ---- epilogue: normalize by deferred denominator, write bf16 ----
  #pragma unroll
  for (int qt = 0; qt < 2; ++qt) {
    float li = lsum[qt];
    li += __shfl_xor(li, 16);
    li += __shfl_xor(li, 32);
    float inv = 1.f / li;                       // denom for q-row l16
    float invr[4];
    #pragma unroll
    for (int r = 0; r < 4; ++r) invr[r] = __shfl(inv, quad * 4 + r, 64);

    const int baserow = (bf << 10) + (qblk << 7) + (wave << 5) + (qt << 4) + quad * 4;
    #pragma unroll
    for (int t = 0; t < 3; ++t) {
      int dcol = t * 16 + l16;
      if (dcol < 40) {
        short* op = AOh + (size_t)baserow * 640 + coff + dcol;
        #pragma unroll
        for (int r = 0; r < 4; ++r)
          op[(size_t)r * 640] = (short)(bfbits(acc[qt][t][r] * invr[r]) >> 16);
      }
    }
  }
}

// ---------------------------------------------------------------------------
extern "C" void kernel_launch(void* const* d_in, const int* in_sizes, int n_in,
                              void* d_out, int out_size, void* d_ws, size_t ws_size,
                              hipStream_t stream) {
  const float* hidden  = (const float*)d_in[0];
  const float* Wq      = (const float*)d_in[1];
  const float* Wk      = (const float*)d_in[2];
  const float* Wv      = (const float*)d_in[3];
  const float* Wo      = (const float*)d_in[4];
  const float* bo      = (const float*)d_in[5];
  const float* Wq_i2v  = (const float*)d_in[6];
  const float* Wo_i2v  = (const float*)d_in[7];
  const float* bo_i2v  = (const float*)d_in[8];
  float* out = (float*)d_out;

  const size_t SZ  = (size_t)MROWS * CDIM;    // 2,621,440
  const size_t SZP = (size_t)MROWS * QPAD;    // 4,194,304
  short* Ah  = (short*)d_ws;                  // [8192][320] split hidden (hi)
  short* Al  = Ah + SZ;                       // [8192][320] (lo)
  short* AOh = Ah;                            // attn out [8192][640] — aliases Ah/Al (dead after G1)
  short* Qp  = Al + SZ;                       // [8192][512] padded
  short* Kp  = Qp + SZP;                      // [8192][512] padded
  short* Qip = Kp + SZP;                      // [8192][512] padded
  short* Vt  = Qip + SZP;                     // [328][8192] (rows 320..327 slack)
  short* WTh = Vt + (size_t)328 * MROWS;
  short* WTl = WTh + 409600;
  short* WFh = WTl + 409600;                  // [320][640] transposed [Wo; Wc]
  short* WFl = WFh + 204800;
  float* Wc  = (float*)(WFl + 204800);
  float* bc  = Wc + 102400;

  const float qscale = 0.15811388300841898f;  // 1/sqrt(40), folded into Q/Q_i2v

  // P1: Wc = Wo_i2v @ Wo
  wc_kernel<<<dim3(5, 5), 256, 0, stream>>>(Wo_i2v, Wo, Wc);

  // P2: split/transpose/zero-pad
  pack_kernel<<<dim3(264), 256, 0, stream>>>(
      hidden, Wq, Wk, Wv, Wq_i2v, Wo, Wc, bo, bo_i2v,
      Ah, Al, WTh, WTl, WFh, WFl, bc, Qp, Kp, Qip, qscale);

  // G1: projections (3-term split MFMA) -> padded Q/K/Qi + V^T
  mfma_gemm<<<dim3(64, 20), 256, 0, stream>>>(
      Ah, Al, WTh, WTl, 320, 0, Qp, Kp, Vt, Qip, nullptr, nullptr);

  // A: both attentions (base: per-frame KV; i2v: frame-0 KV) -> AOh [8192][640]
  attn_kernel<<<dim3(8, 8, 16), 256, 0, stream>>>(Qp, Qip, Kp, Vt, AOh);

  // G2: out = [base|i2v] @ [Wo; Wo_i2v@Wo] + (bo + bo_i2v@Wo), scattered (2-term)
  mfma_gemm<<<dim3(64, 5), 256, 0, stream>>>(
      AOh, nullptr, WFh, WFl, 640, 1, nullptr, nullptr, nullptr, nullptr, out, bc);
}

// Round 9
// 213.666 us; speedup vs baseline: 1.0634x; 1.0634x over previous
//
#include <hip/hip_runtime.h>

// Problem constants: b=1, n=4 views, f=8 frames, l=256, C=320, H=8, d=40
#define MROWS 8192   // (b*f) * (n*l)
#define CDIM  320
#define QPAD  512    // padded row stride for Q/K/Qi: 8 heads x 64 (cols 40..63 zero)

typedef __attribute__((ext_vector_type(8))) short bf16x8;
typedef __attribute__((ext_vector_type(4))) float f32x4;

__device__ __forceinline__ unsigned bfbits(float x) {  // round-half-up bf16 bits (hi16)
  union { float f; unsigned u; } a; a.f = x;
  return a.u + 0x8000u;
}
__device__ __forceinline__ unsigned pack2bf(float a, float b) {
  return (bfbits(a) >> 16) | (bfbits(b) & 0xffff0000u);
}
__device__ __forceinline__ void splitbf(float x, short& hi, short& lo) {
  unsigned hu = bfbits(x) & 0xffff0000u;
  union { unsigned u; float f; } h; h.u = hu;
  hi = (short)(hu >> 16);
  lo = (short)(bfbits(x - h.f) >> 16);
}

// rearrange '(b n f) l c -> (b f) (n l) c' row map (involution)
__device__ __forceinline__ int swizzle_row(int r) {
  int ff = r >> 10;
  int t  = r & 1023;
  int nn = t >> 8;
  int ll = t & 255;
  return nn * 2048 + ff * 256 + ll;
}

// ---------------------------------------------------------------------------
// P1: Wc = Wo_i2v @ Wo, fp32, 64x64 tiles, grid (5,5). Tiny (65 MFLOP).
// ---------------------------------------------------------------------------
__global__ __launch_bounds__(256) void wc_kernel(
    const float* __restrict__ Woi, const float* __restrict__ Wo,
    float* __restrict__ Wc)
{
  const int r0 = blockIdx.x * 64, c0 = blockIdx.y * 64;
  __shared__ float As[64][36];
  __shared__ float Bs[32][68];
  const int tid = threadIdx.x, tx = tid & 15, ty = tid >> 4;
  float acc[4][4] = {};

  const int ra = tid >> 3, kq = (tid & 7) * 4;
  const int kb = tid >> 4, cq = (tid & 15) * 4;

  for (int k0 = 0; k0 < 320; k0 += 32) {
    float4 a1 = *(const float4*)(Woi + (size_t)(r0 + ra) * 320 + k0 + kq);
    float4 a2 = *(const float4*)(Woi + (size_t)(r0 + ra + 32) * 320 + k0 + kq);
    float4 b1 = *(const float4*)(Wo + (size_t)(k0 + kb) * 320 + c0 + cq);
    float4 b2 = *(const float4*)(Wo + (size_t)(k0 + kb + 16) * 320 + c0 + cq);
    __syncthreads();
    *(float4*)&As[ra][kq] = a1;
    *(float4*)&As[ra + 32][kq] = a2;
    *(float4*)&Bs[kb][cq] = b1;
    *(float4*)&Bs[kb + 16][cq] = b2;
    __syncthreads();
    #pragma unroll
    for (int kk = 0; kk < 32; ++kk) {
      float4 bv = *(const float4*)&Bs[kk][tx * 4];
      #pragma unroll
      for (int i = 0; i < 4; ++i) {
        float a = As[ty * 4 + i][kk];
        acc[i][0] = fmaf(a, bv.x, acc[i][0]);
        acc[i][1] = fmaf(a, bv.y, acc[i][1]);
        acc[i][2] = fmaf(a, bv.z, acc[i][2]);
        acc[i][3] = fmaf(a, bv.w, acc[i][3]);
      }
    }
  }
  #pragma unroll
  for (int i = 0; i < 4; ++i) {
    float4 v = make_float4(acc[i][0], acc[i][1], acc[i][2], acc[i][3]);
    *(float4*)(Wc + (size_t)(r0 + ty * 4 + i) * 320 + c0 + tx * 4) = v;
  }
}

// ---------------------------------------------------------------------------
// P2: pack/split/zero everything (identical to round 6).
// ---------------------------------------------------------------------------
__global__ __launch_bounds__(256) void pack_kernel(
    const float* __restrict__ hidden,
    const float* __restrict__ Wq, const float* __restrict__ Wk,
    const float* __restrict__ Wv, const float* __restrict__ Wqi,
    const float* __restrict__ Wo, const float* __restrict__ Wc,
    const float* __restrict__ bo, const float* __restrict__ boi,
    short* __restrict__ Ah, short* __restrict__ Al,
    short* __restrict__ WTh, short* __restrict__ WTl,
    short* __restrict__ WFh, short* __restrict__ WFl,
    float* __restrict__ bc,
    short* __restrict__ Qp, short* __restrict__ Kp, short* __restrict__ Qip,
    float qscale)
{
  const int b = blockIdx.x, tid = threadIdx.x;
  if (b < 64) {
    const int r0 = b * 128;
    for (int e = tid; e < 128 * 80; e += 256) {
      int r = e / 80, cq = (e % 80) * 4;
      float4 x = *(const float4*)(hidden + (size_t)swizzle_row(r0 + r) * 320 + cq);
      union { ushort4 v; short s[4]; } h, l;
      splitbf(x.x, h.s[0], l.s[0]); splitbf(x.y, h.s[1], l.s[1]);
      splitbf(x.z, h.s[2], l.s[2]); splitbf(x.w, h.s[3], l.s[3]);
      *(ushort4*)&Ah[(size_t)(r0 + r) * 320 + cq] = h.v;
      *(ushort4*)&Al[(size_t)(r0 + r) * 320 + cq] = l.v;
    }
  } else if (b < 128) {
    const int t2 = b - 64, wi = t2 >> 4, seg = t2 & 15;
    const float* W = wi == 0 ? Wq : wi == 1 ? Wk : wi == 2 ? Wv : Wqi;
    const float s = (wi == 0 || wi == 3) ? qscale : 1.0f;
    short* th = WTh + (size_t)wi * 320 * 320;
    short* tl = WTl + (size_t)wi * 320 * 320;
    for (int e = tid; e < 20 * 320; e += 256) {
      int n = seg * 20 + e / 320, k = e % 320;
      short hi, lo;
      splitbf(W[(size_t)k * 320 + n] * s, hi, lo);
      th[(size_t)n * 320 + k] = hi;
      tl[(size_t)n * 320 + k] = lo;
    }
  } else if (b < 160) {
    const int t2 = b - 128;
    for (int e = tid; e < 10 * 640; e += 256) {
      int n = t2 * 10 + e / 640, k = e % 640;
      float x = (k < 320) ? Wo[(size_t)k * 320 + n] : Wc[(size_t)(k - 320) * 320 + n];
      short hi, lo;
      splitbf(x, hi, lo);
      WFh[(size_t)n * 640 + k] = hi;
      WFl[(size_t)n * 640 + k] = lo;
    }
  } else if (b < 168) {
    const int n = (b - 160) * 40 + tid;
    if (tid < 40) {
      float s = bo[n];
      for (int j = 0; j < 320; ++j) s = fmaf(boi[j], Wo[(size_t)j * 320 + n], s);
      bc[n] = s;
    }
  } else {
    const int bz = b - 168, buf = bz >> 5, seg = bz & 31;
    short* P = buf == 0 ? Qp : buf == 1 ? Kp : Qip;
    const uint4 z = make_uint4(0, 0, 0, 0);
    for (int e = tid; e < 256 * 24; e += 256) {
      int row = (seg << 8) + (e / 24);
      int cc = e % 24, h = cc / 3, c3 = cc % 3;
      *(uint4*)&P[(size_t)row * QPAD + h * 64 + 40 + c3 * 8] = z;
    }
  }
}

// ---------------------------------------------------------------------------
// Split-bf16 MFMA GEMM (identical to round 6).
// ---------------------------------------------------------------------------
__global__ __launch_bounds__(256, 3) void mfma_gemm(
    const short* __restrict__ Ah, const short* __restrict__ Al,
    const short* __restrict__ BTh, const short* __restrict__ BTl,
    int K, int mode,
    short* __restrict__ Qp, short* __restrict__ Kp,
    short* __restrict__ Vt, short* __restrict__ Qip,
    float* __restrict__ Of, const float* __restrict__ bias)
{
  const int tid  = threadIdx.x;
  const int wave = tid >> 6;
  const int lane = tid & 63;
  const int quad = lane >> 4;
  const int l16  = lane & 15;
  const int row0 = blockIdx.x * 128;

  const short *bth, *btl;
  int nbase, wi = 0;
  if (mode == 0) {
    const int ct = blockIdx.y;
    wi = ct / 5;
    bth = BTh + (size_t)wi * 320 * 320;
    btl = BTl + (size_t)wi * 320 * 320;
    nbase = (ct % 5) * 64;
  } else {
    bth = BTh; btl = BTl;
    nbase = blockIdx.y * 64;
  }

  __shared__ short Ash[128][40], Asl[128][40];
  __shared__ short Bsh[64][40],  Bsl[64][40];

  f32x4 acc[2][4];
  #pragma unroll
  for (int mt = 0; mt < 2; ++mt)
    #pragma unroll
    for (int nt = 0; nt < 4; ++nt) acc[mt][nt] = (f32x4){0.f, 0.f, 0.f, 0.f};

  const int ar = tid >> 2, akc = (tid & 3) * 8;
  const int bn = tid >> 2, bkc = (tid & 3) * 8;

  const short* pa_h = Ah + (size_t)(row0 + ar) * K + akc;
  const short* pa_l = Al ? Al + (size_t)(row0 + ar) * K + akc : nullptr;
  const short* pb_h = bth + (size_t)(nbase + bn) * K + bkc;
  const short* pb_l = btl + (size_t)(nbase + bn) * K + bkc;

  for (int k0 = 0; k0 < K; k0 += 32) {
    uint4 ah1 = *(const uint4*)(pa_h + k0);
    uint4 ah2 = *(const uint4*)(pa_h + (size_t)64 * K + k0);
    uint4 al1, al2;
    if (Al) {
      al1 = *(const uint4*)(pa_l + k0);
      al2 = *(const uint4*)(pa_l + (size_t)64 * K + k0);
    }
    uint4 bh = *(const uint4*)(pb_h + k0);
    uint4 bl = *(const uint4*)(pb_l + k0);
    __syncthreads();
    *(uint4*)&Ash[ar][akc]      = ah1;
    *(uint4*)&Ash[ar + 64][akc] = ah2;
    if (Al) {
      *(uint4*)&Asl[ar][akc]      = al1;
      *(uint4*)&Asl[ar + 64][akc] = al2;
    }
    *(uint4*)&Bsh[bn][bkc] = bh;
    *(uint4*)&Bsl[bn][bkc] = bl;
    __syncthreads();

    bf16x8 afh[2], afl[2], bfh[4], bfl[4];
    #pragma unroll
    for (int mt = 0; mt < 2; ++mt) {
      afh[mt] = *(const bf16x8*)&Ash[wave * 32 + mt * 16 + l16][quad * 8];
      if (Al) afl[mt] = *(const bf16x8*)&Asl[wave * 32 + mt * 16 + l16][quad * 8];
    }
    #pragma unroll
    for (int nt = 0; nt < 4; ++nt) {
      bfh[nt] = *(const bf16x8*)&Bsh[nt * 16 + l16][quad * 8];
      bfl[nt] = *(const bf16x8*)&Bsl[nt * 16 + l16][quad * 8];
    }
    #pragma unroll
    for (int mt = 0; mt < 2; ++mt)
      #pragma unroll
      for (int nt = 0; nt < 4; ++nt) {
        acc[mt][nt] = __builtin_amdgcn_mfma_f32_16x16x32_bf16(afh[mt], bfh[nt], acc[mt][nt], 0, 0, 0);
        acc[mt][nt] = __builtin_amdgcn_mfma_f32_16x16x32_bf16(afh[mt], bfl[nt], acc[mt][nt], 0, 0, 0);
        if (Al)
          acc[mt][nt] = __builtin_amdgcn_mfma_f32_16x16x32_bf16(afl[mt], bfh[nt], acc[mt][nt], 0, 0, 0);
      }
  }

  if (mode == 0) {
    if (wi == 2) {
      #pragma unroll
      for (int mt = 0; mt < 2; ++mt)
        #pragma unroll
        for (int nt = 0; nt < 4; ++nt) {
          const int col  = nbase + nt * 16 + l16;
          const int rowb = row0 + wave * 32 + mt * 16 + quad * 4;
          union { ushort4 v; short s[4]; } pk;
          #pragma unroll
          for (int r = 0; r < 4; ++r) pk.s[r] = (short)(bfbits(acc[mt][nt][r]) >> 16);
          *(ushort4*)&Vt[(size_t)col * MROWS + rowb] = pk.v;
        }
    } else {
      short* Op = wi == 0 ? Qp : wi == 1 ? Kp : Qip;
      #pragma unroll
      for (int mt = 0; mt < 2; ++mt)
        #pragma unroll
        for (int nt = 0; nt < 4; ++nt) {
          const int col  = nbase + nt * 16 + l16;
          const int h    = col / 40;
          const int pcol = h * 64 + (col - h * 40);
          const int rowb = row0 + wave * 32 + mt * 16 + quad * 4;
          #pragma unroll
          for (int r = 0; r < 4; ++r)
            Op[(size_t)(rowb + r) * QPAD + pcol] = (short)(bfbits(acc[mt][nt][r]) >> 16);
        }
    }
  } else {
    #pragma unroll
    for (int mt = 0; mt < 2; ++mt)
      #pragma unroll
      for (int nt = 0; nt < 4; ++nt) {
        const int col  = nbase + nt * 16 + l16;
        const int rowb = row0 + wave * 32 + mt * 16 + quad * 4;
        const float bb = bias[col];
        #pragma unroll
        for (int r = 0; r < 4; ++r)
          Of[(size_t)swizzle_row(rowb + r) * CDIM + col] = acc[mt][nt][r] + bb;
      }
  }
}

// ---------------------------------------------------------------------------
// Flash attention, bf16 MFMA, static-max softmax. Round-6 numerics/topology
// (4 waves, 32 q-rows/wave, 64-key LDS steps, kt*16+l16 key map) with:
//  - NO register prefetch (round-8 regression: L2 thrash + overshoot fetch)
//  - hoisted 5-chunk K staging (40 cols; Ks pad cols zeroed once)
//  - Ps row stride 68 shorts (34 words): b64 P-store banks 2*(l16+quad)%32
//    -> 2 words/bank = conflict-FREE (72-stride was 4-way)
//  - qt-OUTER loop with single-qt Ps[4][16][68]: LDS 34.8 -> 24.8 KB
//    -> 4+ blocks/CU. DS ops are wave-in-order so WAR across qt is safe.
// grid = (8 qblk, 8 heads, 16 = bf + 8*variant).
// ---------------------------------------------------------------------------
__global__ __launch_bounds__(256, 4) void attn_kernel(
    const short* __restrict__ Qp, const short* __restrict__ Qip,
    const short* __restrict__ Kp, const short* __restrict__ Vtg,
    short* __restrict__ AOh)
{
  const int qblk = blockIdx.x;   // 0..7 (128 q-rows per block)
  const int hh   = blockIdx.y;   // 0..7
  const int zz   = blockIdx.z;   // 0..15
  const int var  = zz >> 3;
  const int bf   = zz & 7;
  const int tid  = threadIdx.x;
  const int wave = tid >> 6;
  const int lane = tid & 63;
  const int quad = lane >> 4;
  const int l16  = lane & 15;

  const short* Q = var ? Qip : Qp;
  const int kvbase = var ? 0 : (bf << 10);
  const int coff = var * 320 + hh * 40;

  __shared__ short Ks[64][72];    // [key][kd], cols 40..71 zero
  __shared__ short Vt[48][72];    // [dcol][key], rows 40..47 zero
  __shared__ short Ps[4][16][68]; // per-wave P buffer (one q-tile at a time)

  // zero pad regions once (staging never writes them)
  *(uint4*)&Ks[tid >> 2][40 + (tid & 3) * 8] = make_uint4(0, 0, 0, 0);
  if (tid < 64)
    *(uint4*)&Vt[40 + (tid >> 3)][(tid & 7) * 8] = make_uint4(0, 0, 0, 0);

  // Q B-fragments: 2 q-tiles of 16 rows; n = l16 = q-row, k = quad*8+j
  bf16x8 qf0[2], qf1[2];
  #pragma unroll
  for (int qt = 0; qt < 2; ++qt) {
    const short* qp = Q + (size_t)((bf << 10) + (qblk << 7) + (wave << 5) + (qt << 4) + l16) * QPAD + hh * 64;
    qf0[qt] = *(const bf16x8*)(qp + quad * 8);
    qf1[qt] = *(const bf16x8*)(qp + 32 + quad * 8);
  }

  f32x4 acc[2][3];
  float lsum[2] = {0.f, 0.f};
  #pragma unroll
  for (int qt = 0; qt < 2; ++qt)
    #pragma unroll
    for (int t = 0; t < 3; ++t) acc[qt][t] = (f32x4){0.f, 0.f, 0.f, 0.f};

  const short* Kb = Kp + (size_t)kvbase * QPAD + hh * 64;
  const short* Vb = Vtg + (size_t)(hh * 40) * MROWS + kvbase;

  // ---- staging pointers, hoisted (roles wave-uniform) ----
  // p1: all threads -> K units 0..255 (key=tid/5, c=tid%5; 40 cols only)
  // p2: wave0 -> K units 256..319; waves1-3 -> V units 0..191
  // p3: waves0-1 -> V units 192..319; waves2-3 idle
  const int k1 = tid / 5, c1 = tid % 5;
  const short* g1 = Kb + (size_t)k1 * QPAD + c1 * 8;
  short*       s1 = &Ks[k1][c1 * 8];
  const short* g2; short* s2; size_t inc2;
  if (tid < 64) {
    int u = tid + 256, k2 = u / 5, c2 = u % 5;
    g2 = Kb + (size_t)k2 * QPAD + c2 * 8;
    s2 = &Ks[k2][c2 * 8];
    inc2 = (size_t)64 * QPAD;
  } else {
    int v = tid - 64;
    g2 = Vb + (size_t)(v >> 3) * MROWS + (v & 7) * 8;
    s2 = &Vt[v >> 3][(v & 7) * 8];
    inc2 = 64;
  }
  const short* g3 = nullptr; short* s3 = nullptr;
  if (tid < 128) {
    int v = tid + 192;
    g3 = Vb + (size_t)(v >> 3) * MROWS + (v & 7) * 8;
    s3 = &Vt[v >> 3][(v & 7) * 8];
  }

  for (int step = 0; step < 16; ++step) {
    __syncthreads();                 // previous step fully consumed
    *(uint4*)s1 = *(const uint4*)g1;  g1 += (size_t)64 * QPAD;
    *(uint4*)s2 = *(const uint4*)g2;  g2 += inc2;
    if (tid < 128) { *(uint4*)s3 = *(const uint4*)g3;  g3 += 64; }
    __syncthreads();                 // staging visible

    // V B-fragments (shared across q-tiles)
    bf16x8 vf[2][3];
    #pragma unroll
    for (int kh = 0; kh < 2; ++kh)
      #pragma unroll
      for (int t = 0; t < 3; ++t)
        vf[kh][t] = *(const bf16x8*)&Vt[t * 16 + l16][kh * 32 + quad * 8];

    #pragma unroll
    for (int qt = 0; qt < 2; ++qt) {
      // ---- QK^T + exp + pack, per kt (K frags transient) ----
      #pragma unroll
      for (int kt = 0; kt < 4; ++kt) {
        const short* kr = &Ks[kt * 16 + l16][quad * 8];
        bf16x8 kb0 = *(const bf16x8*)kr;
        bf16x8 kb1 = *(const bf16x8*)(kr + 32);
        f32x4 st = (f32x4){0.f, 0.f, 0.f, 0.f};
        st = __builtin_amdgcn_mfma_f32_16x16x32_bf16(kb0, qf0[qt], st, 0, 0, 0);
        st = __builtin_amdgcn_mfma_f32_16x16x32_bf16(kb1, qf1[qt], st, 0, 0, 0);
        float p0 = __expf(st[0]);
        float p1 = __expf(st[1]);
        float p2 = __expf(st[2]);
        float p3 = __expf(st[3]);
        lsum[qt] += (p0 + p1) + (p2 + p3);
        uint2 pk;
        pk.x = pack2bf(p0, p1);
        pk.y = pack2bf(p2, p3);
        // keys kt*16 + quad*4 + {0..3} for q-row l16 (stride-68 rows)
        *(uint2*)&Ps[wave][l16][kt * 16 + quad * 4] = pk;
      }

      // wave-internal LDS RAW (cross-lane): drain before reading P
      asm volatile("s_waitcnt lgkmcnt(0)" ::: "memory");

      // ---- P @ V ----
      bf16x8 pa0 = *(const bf16x8*)&Ps[wave][l16][quad * 8];
      bf16x8 pa1 = *(const bf16x8*)&Ps[wave][l16][32 + quad * 8];
      #pragma unroll
      for (int t = 0; t < 3; ++t) {
        acc[qt][t] = __builtin_amdgcn_mfma_f32_16x16x32_bf16(pa0, vf[0][t], acc[qt][t], 0, 0, 0);
        acc[qt][t] = __builtin_amdgcn_mfma_f32_16x16x32_bf16(pa1, vf[1][t], acc[qt][t], 0, 0, 0);
      }
      // NOTE: next qt's Ps writes are safe (DS ops in-order within a wave)
    }
  }

  // ---- epilogue: normalize by deferred denominator, write bf16 ----
  #pragma unroll
  for (int qt = 0; qt < 2; ++qt) {
    float li = lsum[qt];
    li += __shfl_xor(li, 16);
    li += __shfl_xor(li, 32);
    float inv = 1.f / li;                       // denom for q-row l16
    float invr[4];
    #pragma unroll
    for (int r = 0; r < 4; ++r) invr[r] = __shfl(inv, quad * 4 + r, 64);

    const int baserow = (bf << 10) + (qblk << 7) + (wave << 5) + (qt << 4) + quad * 4;
    #pragma unroll
    for (int t = 0; t < 3; ++t) {
      int dcol = t * 16 + l16;
      if (dcol < 40) {
        short* op = AOh + (size_t)baserow * 640 + coff + dcol;
        #pragma unroll
        for (int r = 0; r < 4; ++r)
          op[(size_t)r * 640] = (short)(bfbits(acc[qt][t][r] * invr[r]) >> 16);
      }
    }
  }
}

// ---------------------------------------------------------------------------
extern "C" void kernel_launch(void* const* d_in, const int* in_sizes, int n_in,
                              void* d_out, int out_size, void* d_ws, size_t ws_size,
                              hipStream_t stream) {
  const float* hidden  = (const float*)d_in[0];
  const float* Wq      = (const float*)d_in[1];
  const float* Wk      = (const float*)d_in[2];
  const float* Wv      = (const float*)d_in[3];
  const float* Wo      = (const float*)d_in[4];
  const float* bo      = (const float*)d_in[5];
  const float* Wq_i2v  = (const float*)d_in[6];
  const float* Wo_i2v  = (const float*)d_in[7];
  const float* bo_i2v  = (const float*)d_in[8];
  float* out = (float*)d_out;

  const size_t SZ  = (size_t)MROWS * CDIM;    // 2,621,440
  const size_t SZP = (size_t)MROWS * QPAD;    // 4,194,304
  short* Ah  = (short*)d_ws;                  // [8192][320] split hidden (hi)
  short* Al  = Ah + SZ;                       // [8192][320] (lo)
  short* AOh = Ah;                            // attn out [8192][640] — aliases Ah/Al (dead after G1)
  short* Qp  = Al + SZ;                       // [8192][512] padded
  short* Kp  = Qp + SZP;                      // [8192][512] padded
  short* Qip = Kp + SZP;                      // [8192][512] padded
  short* Vt  = Qip + SZP;                     // [328][8192] (rows 320..327 slack)
  short* WTh = Vt + (size_t)328 * MROWS;
  short* WTl = WTh + 409600;
  short* WFh = WTl + 409600;                  // [320][640] transposed [Wo; Wc]
  short* WFl = WFh + 204800;
  float* Wc  = (float*)(WFl + 204800);
  float* bc  = Wc + 102400;

  const float qscale = 0.15811388300841898f;  // 1/sqrt(40), folded into Q/Q_i2v

  // P1: Wc = Wo_i2v @ Wo
  wc_kernel<<<dim3(5, 5), 256, 0, stream>>>(Wo_i2v, Wo, Wc);

  // P2: split/transpose/zero-pad
  pack_kernel<<<dim3(264), 256, 0, stream>>>(
      hidden, Wq, Wk, Wv, Wq_i2v, Wo, Wc, bo, bo_i2v,
      Ah, Al, WTh, WTl, WFh, WFl, bc, Qp, Kp, Qip, qscale);

  // G1: projections (3-term split MFMA) -> padded Q/K/Qi + V^T
  mfma_gemm<<<dim3(64, 20), 256, 0, stream>>>(
      Ah, Al, WTh, WTl, 320, 0, Qp, Kp, Vt, Qip, nullptr, nullptr);

  // A: both attentions (base: per-frame KV; i2v: frame-0 KV) -> AOh [8192][640]
  attn_kernel<<<dim3(8, 8, 16), 256, 0, stream>>>(Qp, Qip, Kp, Vt, AOh);

  // G2: out = [base|i2v] @ [Wo; Wo_i2v@Wo] + (bo + bo_i2v@Wo), scattered (2-term)
  mfma_gemm<<<dim3(64, 5), 256, 0, stream>>>(
      AOh, nullptr, WFh, WFl, 640, 1, nullptr, nullptr, nullptr, nullptr, out, bc);
}

// Round 10
// 209.706 us; speedup vs baseline: 1.0835x; 1.0189x over previous
//
#include <hip/hip_runtime.h>

// Problem constants: b=1, n=4 views, f=8 frames, l=256, C=320, H=8, d=40
#define MROWS 8192   // (b*f) * (n*l)
#define CDIM  320
#define QPAD  512    // padded row stride for Q/K/Qi: 8 heads x 64 (cols 40..63 zero)

typedef __attribute__((ext_vector_type(8))) short bf16x8;
typedef __attribute__((ext_vector_type(4))) float f32x4;

__device__ __forceinline__ unsigned bfbits(float x) {  // round-half-up bf16 bits (hi16)
  union { float f; unsigned u; } a; a.f = x;
  return a.u + 0x8000u;
}
__device__ __forceinline__ unsigned pack2bf(float a, float b) {
  return (bfbits(a) >> 16) | (bfbits(b) & 0xffff0000u);
}
__device__ __forceinline__ void splitbf(float x, short& hi, short& lo) {
  unsigned hu = bfbits(x) & 0xffff0000u;
  union { unsigned u; float f; } h; h.u = hu;
  hi = (short)(hu >> 16);
  lo = (short)(bfbits(x - h.f) >> 16);
}

// async global->LDS DMA, 16B/lane; LDS dest = wave-uniform base + lane*16
__device__ __forceinline__ void cp16_g2l(const void* g, void* l) {
  __builtin_amdgcn_global_load_lds(
      (const __attribute__((address_space(1))) void*)g,
      (__attribute__((address_space(3))) void*)l, 16, 0, 0);
}

// rearrange '(b n f) l c -> (b f) (n l) c' row map (involution)
__device__ __forceinline__ int swizzle_row(int r) {
  int ff = r >> 10;
  int t  = r & 1023;
  int nn = t >> 8;
  int ll = t & 255;
  return nn * 2048 + ff * 256 + ll;
}

// ---------------------------------------------------------------------------
// P1: Wc = Wo_i2v @ Wo, fp32, 64x64 tiles, grid (5,5). Tiny (65 MFLOP).
// ---------------------------------------------------------------------------
__global__ __launch_bounds__(256) void wc_kernel(
    const float* __restrict__ Woi, const float* __restrict__ Wo,
    float* __restrict__ Wc)
{
  const int r0 = blockIdx.x * 64, c0 = blockIdx.y * 64;
  __shared__ float As[64][36];
  __shared__ float Bs[32][68];
  const int tid = threadIdx.x, tx = tid & 15, ty = tid >> 4;
  float acc[4][4] = {};

  const int ra = tid >> 3, kq = (tid & 7) * 4;
  const int kb = tid >> 4, cq = (tid & 15) * 4;

  for (int k0 = 0; k0 < 320; k0 += 32) {
    float4 a1 = *(const float4*)(Woi + (size_t)(r0 + ra) * 320 + k0 + kq);
    float4 a2 = *(const float4*)(Woi + (size_t)(r0 + ra + 32) * 320 + k0 + kq);
    float4 b1 = *(const float4*)(Wo + (size_t)(k0 + kb) * 320 + c0 + cq);
    float4 b2 = *(const float4*)(Wo + (size_t)(k0 + kb + 16) * 320 + c0 + cq);
    __syncthreads();
    *(float4*)&As[ra][kq] = a1;
    *(float4*)&As[ra + 32][kq] = a2;
    *(float4*)&Bs[kb][cq] = b1;
    *(float4*)&Bs[kb + 16][cq] = b2;
    __syncthreads();
    #pragma unroll
    for (int kk = 0; kk < 32; ++kk) {
      float4 bv = *(const float4*)&Bs[kk][tx * 4];
      #pragma unroll
      for (int i = 0; i < 4; ++i) {
        float a = As[ty * 4 + i][kk];
        acc[i][0] = fmaf(a, bv.x, acc[i][0]);
        acc[i][1] = fmaf(a, bv.y, acc[i][1]);
        acc[i][2] = fmaf(a, bv.z, acc[i][2]);
        acc[i][3] = fmaf(a, bv.w, acc[i][3]);
      }
    }
  }
  #pragma unroll
  for (int i = 0; i < 4; ++i) {
    float4 v = make_float4(acc[i][0], acc[i][1], acc[i][2], acc[i][3]);
    *(float4*)(Wc + (size_t)(r0 + ty * 4 + i) * 320 + c0 + tx * 4) = v;
  }
}

// ---------------------------------------------------------------------------
// P2: pack/split/zero everything (identical to round 6).
// ---------------------------------------------------------------------------
__global__ __launch_bounds__(256) void pack_kernel(
    const float* __restrict__ hidden,
    const float* __restrict__ Wq, const float* __restrict__ Wk,
    const float* __restrict__ Wv, const float* __restrict__ Wqi,
    const float* __restrict__ Wo, const float* __restrict__ Wc,
    const float* __restrict__ bo, const float* __restrict__ boi,
    short* __restrict__ Ah, short* __restrict__ Al,
    short* __restrict__ WTh, short* __restrict__ WTl,
    short* __restrict__ WFh, short* __restrict__ WFl,
    float* __restrict__ bc,
    short* __restrict__ Qp, short* __restrict__ Kp, short* __restrict__ Qip,
    float qscale)
{
  const int b = blockIdx.x, tid = threadIdx.x;
  if (b < 64) {
    const int r0 = b * 128;
    for (int e = tid; e < 128 * 80; e += 256) {
      int r = e / 80, cq = (e % 80) * 4;
      float4 x = *(const float4*)(hidden + (size_t)swizzle_row(r0 + r) * 320 + cq);
      union { ushort4 v; short s[4]; } h, l;
      splitbf(x.x, h.s[0], l.s[0]); splitbf(x.y, h.s[1], l.s[1]);
      splitbf(x.z, h.s[2], l.s[2]); splitbf(x.w, h.s[3], l.s[3]);
      *(ushort4*)&Ah[(size_t)(r0 + r) * 320 + cq] = h.v;
      *(ushort4*)&Al[(size_t)(r0 + r) * 320 + cq] = l.v;
    }
  } else if (b < 128) {
    const int t2 = b - 64, wi = t2 >> 4, seg = t2 & 15;
    const float* W = wi == 0 ? Wq : wi == 1 ? Wk : wi == 2 ? Wv : Wqi;
    const float s = (wi == 0 || wi == 3) ? qscale : 1.0f;
    short* th = WTh + (size_t)wi * 320 * 320;
    short* tl = WTl + (size_t)wi * 320 * 320;
    for (int e = tid; e < 20 * 320; e += 256) {
      int n = seg * 20 + e / 320, k = e % 320;
      short hi, lo;
      splitbf(W[(size_t)k * 320 + n] * s, hi, lo);
      th[(size_t)n * 320 + k] = hi;
      tl[(size_t)n * 320 + k] = lo;
    }
  } else if (b < 160) {
    const int t2 = b - 128;
    for (int e = tid; e < 10 * 640; e += 256) {
      int n = t2 * 10 + e / 640, k = e % 640;
      float x = (k < 320) ? Wo[(size_t)k * 320 + n] : Wc[(size_t)(k - 320) * 320 + n];
      short hi, lo;
      splitbf(x, hi, lo);
      WFh[(size_t)n * 640 + k] = hi;
      WFl[(size_t)n * 640 + k] = lo;
    }
  } else if (b < 168) {
    const int n = (b - 160) * 40 + tid;
    if (tid < 40) {
      float s = bo[n];
      for (int j = 0; j < 320; ++j) s = fmaf(boi[j], Wo[(size_t)j * 320 + n], s);
      bc[n] = s;
    }
  } else {
    const int bz = b - 168, buf = bz >> 5, seg = bz & 31;
    short* P = buf == 0 ? Qp : buf == 1 ? Kp : Qip;
    const uint4 z = make_uint4(0, 0, 0, 0);
    for (int e = tid; e < 256 * 24; e += 256) {
      int row = (seg << 8) + (e / 24);
      int cc = e % 24, h = cc / 3, c3 = cc % 3;
      *(uint4*)&P[(size_t)row * QPAD + h * 64 + 40 + c3 * 8] = z;
    }
  }
}

// ---------------------------------------------------------------------------
// Split-bf16 MFMA GEMM with global_load_lds(16B) staging (no VGPR round-trip,
// no ds_write). Unpadded 32-short tile rows are lane-contiguous per wave;
// fragment reads at stride 16 words give exactly 8 words/bank (conflict-free).
// Al != null -> 3-term (AhBh+AhBl+AlBh); Al == null -> 2-term (AhBh+AhBl).
// mode 0 (proj, grid.y=20): bf16 out into PADDED [8192][512] (Q/K/Qi) or
//   transposed V^T[c][8192] (wi==2). mode 1 (final, grid.y=5): K=640,
//   fp32 out + bias + row scatter.
// ---------------------------------------------------------------------------
__global__ __launch_bounds__(256, 3) void mfma_gemm(
    const short* __restrict__ Ah, const short* __restrict__ Al,
    const short* __restrict__ BTh, const short* __restrict__ BTl,
    int K, int mode,
    short* __restrict__ Qp, short* __restrict__ Kp,
    short* __restrict__ Vt, short* __restrict__ Qip,
    float* __restrict__ Of, const float* __restrict__ bias)
{
  const int tid  = threadIdx.x;
  const int wave = tid >> 6;
  const int lane = tid & 63;
  const int quad = lane >> 4;
  const int l16  = lane & 15;
  const int row0 = blockIdx.x * 128;

  const short *bth, *btl;
  int nbase, wi = 0;
  if (mode == 0) {
    const int ct = blockIdx.y;
    wi = ct / 5;
    bth = BTh + (size_t)wi * 320 * 320;
    btl = BTl + (size_t)wi * 320 * 320;
    nbase = (ct % 5) * 64;
  } else {
    bth = BTh; btl = BTl;
    nbase = blockIdx.y * 64;
  }

  __shared__ short Ash[128][32], Asl[128][32];
  __shared__ short Bsh[64][32],  Bsl[64][32];

  f32x4 acc[2][4];
  #pragma unroll
  for (int mt = 0; mt < 2; ++mt)
    #pragma unroll
    for (int nt = 0; nt < 4; ++nt) acc[mt][nt] = (f32x4){0.f, 0.f, 0.f, 0.f};

  // per-lane global sources (row = wave*16 + lane/4, chunk = lane%4)
  const int lr = lane >> 2, lc = (lane & 3) * 8;
  const short* gah = Ah + (size_t)(row0 + wave * 16 + lr) * K + lc;
  const short* gal = Al ? Al + (size_t)(row0 + wave * 16 + lr) * K + lc : nullptr;
  const short* gbh = bth + (size_t)(nbase + wave * 16 + lr) * K + lc;
  const short* gbl = btl + (size_t)(nbase + wave * 16 + lr) * K + lc;
  // wave-uniform LDS bases
  short* lah1 = &Ash[wave * 16][0];
  short* lah2 = &Ash[64 + wave * 16][0];
  short* lal1 = &Asl[wave * 16][0];
  short* lal2 = &Asl[64 + wave * 16][0];
  short* lbh  = &Bsh[wave * 16][0];
  short* lbl  = &Bsl[wave * 16][0];

  for (int k0 = 0; k0 < K; k0 += 32) {
    __syncthreads();                      // previous tile fully consumed
    cp16_g2l(gah + k0, lah1);
    cp16_g2l(gah + (size_t)64 * K + k0, lah2);
    if (Al) {
      cp16_g2l(gal + k0, lal1);
      cp16_g2l(gal + (size_t)64 * K + k0, lal2);
    }
    cp16_g2l(gbh + k0, lbh);
    cp16_g2l(gbl + k0, lbl);
    __syncthreads();                      // vmcnt drained + visible

    bf16x8 afh[2], afl[2], bfh[4], bfl[4];
    #pragma unroll
    for (int mt = 0; mt < 2; ++mt) {
      afh[mt] = *(const bf16x8*)&Ash[wave * 32 + mt * 16 + l16][quad * 8];
      if (Al) afl[mt] = *(const bf16x8*)&Asl[wave * 32 + mt * 16 + l16][quad * 8];
    }
    #pragma unroll
    for (int nt = 0; nt < 4; ++nt) {
      bfh[nt] = *(const bf16x8*)&Bsh[nt * 16 + l16][quad * 8];
      bfl[nt] = *(const bf16x8*)&Bsl[nt * 16 + l16][quad * 8];
    }
    #pragma unroll
    for (int mt = 0; mt < 2; ++mt)
      #pragma unroll
      for (int nt = 0; nt < 4; ++nt) {
        acc[mt][nt] = __builtin_amdgcn_mfma_f32_16x16x32_bf16(afh[mt], bfh[nt], acc[mt][nt], 0, 0, 0);
        acc[mt][nt] = __builtin_amdgcn_mfma_f32_16x16x32_bf16(afh[mt], bfl[nt], acc[mt][nt], 0, 0, 0);
        if (Al)
          acc[mt][nt] = __builtin_amdgcn_mfma_f32_16x16x32_bf16(afl[mt], bfh[nt], acc[mt][nt], 0, 0, 0);
      }
  }

  if (mode == 0) {
    if (wi == 2) {
      #pragma unroll
      for (int mt = 0; mt < 2; ++mt)
        #pragma unroll
        for (int nt = 0; nt < 4; ++nt) {
          const int col  = nbase + nt * 16 + l16;
          const int rowb = row0 + wave * 32 + mt * 16 + quad * 4;
          union { ushort4 v; short s[4]; } pk;
          #pragma unroll
          for (int r = 0; r < 4; ++r) pk.s[r] = (short)(bfbits(acc[mt][nt][r]) >> 16);
          *(ushort4*)&Vt[(size_t)col * MROWS + rowb] = pk.v;
        }
    } else {
      short* Op = wi == 0 ? Qp : wi == 1 ? Kp : Qip;
      #pragma unroll
      for (int mt = 0; mt < 2; ++mt)
        #pragma unroll
        for (int nt = 0; nt < 4; ++nt) {
          const int col  = nbase + nt * 16 + l16;
          const int h    = col / 40;
          const int pcol = h * 64 + (col - h * 40);
          const int rowb = row0 + wave * 32 + mt * 16 + quad * 4;
          #pragma unroll
          for (int r = 0; r < 4; ++r)
            Op[(size_t)(rowb + r) * QPAD + pcol] = (short)(bfbits(acc[mt][nt][r]) >> 16);
        }
    }
  } else {
    #pragma unroll
    for (int mt = 0; mt < 2; ++mt)
      #pragma unroll
      for (int nt = 0; nt < 4; ++nt) {
        const int col  = nbase + nt * 16 + l16;
        const int rowb = row0 + wave * 32 + mt * 16 + quad * 4;
        const float bb = bias[col];
        #pragma unroll
        for (int r = 0; r < 4; ++r)
          Of[(size_t)swizzle_row(rowb + r) * CDIM + col] = acc[mt][nt][r] + bb;
      }
  }
}

// ---------------------------------------------------------------------------
// Flash attention, bf16 MFMA, static-max softmax. Round-9 numerics/topology
// with global_load_lds K/V staging:
//  - Ks[64][64] staged from padded Kp (full rows, zeros included), Vt[48][64]
//    from V^T; 13 wave-level DMA passes (K: 8, V: 5), no ds_write staging.
//  - XOR chunk swizzle applied on the GLOBAL side (per-lane addresses):
//    LDS[row][c] holds global chunk c^(row&7); fragment reads use
//    [(c^ (l16&7))*8] -> uniform 8 words/bank, conflict-free at stride 32w.
//  - Ps stride 68, qt-outer single-qt buffer (round 9).
// grid = (8 qblk, 8 heads, 16 = bf + 8*variant).
// ---------------------------------------------------------------------------
__global__ __launch_bounds__(256, 4) void attn_kernel(
    const short* __restrict__ Qp, const short* __restrict__ Qip,
    const short* __restrict__ Kp, const short* __restrict__ Vtg,
    short* __restrict__ AOh)
{
  const int qblk = blockIdx.x;   // 0..7 (128 q-rows per block)
  const int hh   = blockIdx.y;   // 0..7
  const int zz   = blockIdx.z;   // 0..15
  const int var  = zz >> 3;
  const int bf   = zz & 7;
  const int tid  = threadIdx.x;
  const int wave = tid >> 6;
  const int lane = tid & 63;
  const int quad = lane >> 4;
  const int l16  = lane & 15;

  const short* Q = var ? Qip : Qp;
  const int kvbase = var ? 0 : (bf << 10);
  const int coff = var * 320 + hh * 40;

  __shared__ short Ks[64][64];    // [key][kd], cols 40..63 zero (from Kp pad)
  __shared__ short Vt[48][64];    // [dcol][key], rows 40..47 zero
  __shared__ short Ps[4][16][68]; // per-wave P buffer (one q-tile at a time)

  // zero Vt pad rows once (DMA never writes them)
  if (tid < 64)
    *(uint4*)&Vt[40 + (tid >> 3)][(tid & 7) * 8] = make_uint4(0, 0, 0, 0);

  // Q B-fragments: 2 q-tiles of 16 rows; n = l16 = q-row, k = quad*8+j
  bf16x8 qf0[2], qf1[2];
  #pragma unroll
  for (int qt = 0; qt < 2; ++qt) {
    const short* qp = Q + (size_t)((bf << 10) + (qblk << 7) + (wave << 5) + (qt << 4) + l16) * QPAD + hh * 64;
    qf0[qt] = *(const bf16x8*)(qp + quad * 8);
    qf1[qt] = *(const bf16x8*)(qp + 32 + quad * 8);
  }

  f32x4 acc[2][3];
  float lsum[2] = {0.f, 0.f};
  #pragma unroll
  for (int qt = 0; qt < 2; ++qt)
    #pragma unroll
    for (int t = 0; t < 3; ++t) acc[qt][t] = (f32x4){0.f, 0.f, 0.f, 0.f};

  const short* Kb = Kp + (size_t)kvbase * QPAD + hh * 64;
  const short* Vb = Vtg + (size_t)(hh * 40) * MROWS + kvbase;

  // DMA lane geometry: row = base + lane/8, LDS chunk = lane%8,
  // global chunk = (lane%8) ^ ((lane/8)&7)   (XOR swizzle on global side)
  const int lrow = lane >> 3;
  const int gch  = ((lane & 7) ^ (lrow & 7)) * 8;
  const int sw   = l16 & 7;   // row&7 for fragment-read de-swizzle

  for (int s0 = 0; s0 < 1024; s0 += 64) {
    __syncthreads();                 // previous step fully consumed
    #pragma unroll
    for (int j = 0; j < 4; ++j) {
      const int u = j * 4 + wave;    // wave-uniform unit id
      if (u < 8) {                   // K rows u*8 .. u*8+7
        cp16_g2l(Kb + (size_t)(s0 + u * 8 + lrow) * QPAD + gch, &Ks[u * 8][0]);
      } else if (u < 13) {           // V d-rows (u-8)*8 ..
        cp16_g2l(Vb + (size_t)((u - 8) * 8 + lrow) * MROWS + s0 + gch, &Vt[(u - 8) * 8][0]);
      }
    }
    __syncthreads();                 // vmcnt drained + visible

    // V B-fragments (shared across q-tiles), de-swizzled chunk index
    bf16x8 vf[2][3];
    #pragma unroll
    for (int kh = 0; kh < 2; ++kh)
      #pragma unroll
      for (int t = 0; t < 3; ++t)
        vf[kh][t] = *(const bf16x8*)&Vt[t * 16 + l16][((kh * 4 + quad) ^ sw) * 8];

    #pragma unroll
    for (int qt = 0; qt < 2; ++qt) {
      // ---- QK^T + exp + pack, per kt (K frags transient) ----
      #pragma unroll
      for (int kt = 0; kt < 4; ++kt) {
        const short* kr = &Ks[kt * 16 + l16][0];
        bf16x8 kb0 = *(const bf16x8*)(kr + (quad ^ sw) * 8);
        bf16x8 kb1 = *(const bf16x8*)(kr + ((quad + 4) ^ sw) * 8);
        f32x4 st = (f32x4){0.f, 0.f, 0.f, 0.f};
        st = __builtin_amdgcn_mfma_f32_16x16x32_bf16(kb0, qf0[qt], st, 0, 0, 0);
        st = __builtin_amdgcn_mfma_f32_16x16x32_bf16(kb1, qf1[qt], st, 0, 0, 0);
        float p0 = __expf(st[0]);
        float p1 = __expf(st[1]);
        float p2 = __expf(st[2]);
        float p3 = __expf(st[3]);
        lsum[qt] += (p0 + p1) + (p2 + p3);
        uint2 pk;
        pk.x = pack2bf(p0, p1);
        pk.y = pack2bf(p2, p3);
        // keys kt*16 + quad*4 + {0..3} for q-row l16 (stride-68 rows)
        *(uint2*)&Ps[wave][l16][kt * 16 + quad * 4] = pk;
      }

      // wave-internal LDS RAW (cross-lane): drain before reading P
      asm volatile("s_waitcnt lgkmcnt(0)" ::: "memory");

      // ---- P @ V ----
      bf16x8 pa0 = *(const bf16x8*)&Ps[wave][l16][quad * 8];
      bf16x8 pa1 = *(const bf16x8*)&Ps[wave][l16][32 + quad * 8];
      #pragma unroll
      for (int t = 0; t < 3; ++t) {
        acc[qt][t] = __builtin_amdgcn_mfma_f32_16x16x32_bf16(pa0, vf[0][t], acc[qt][t], 0, 0, 0);
        acc[qt][t] = __builtin_amdgcn_mfma_f32_16x16x32_bf16(pa1, vf[1][t], acc[qt][t], 0, 0, 0);
      }
      // next qt's Ps writes are safe (DS ops in-order within a wave)
    }
  }

  // ---- epilogue: normalize by deferred denominator, write bf16 ----
  #pragma unroll
  for (int qt = 0; qt < 2; ++qt) {
    float li = lsum[qt];
    li += __shfl_xor(li, 16);
    li += __shfl_xor(li, 32);
    float inv = 1.f / li;                       // denom for q-row l16
    float invr[4];
    #pragma unroll
    for (int r = 0; r < 4; ++r) invr[r] = __shfl(inv, quad * 4 + r, 64);

    const int baserow = (bf << 10) + (qblk << 7) + (wave << 5) + (qt << 4) + quad * 4;
    #pragma unroll
    for (int t = 0; t < 3; ++t) {
      int dcol = t * 16 + l16;
      if (dcol < 40) {
        short* op = AOh + (size_t)baserow * 640 + coff + dcol;
        #pragma unroll
        for (int r = 0; r < 4; ++r)
          op[(size_t)r * 640] = (short)(bfbits(acc[qt][t][r] * invr[r]) >> 16);
      }
    }
  }
}

// ---------------------------------------------------------------------------
extern "C" void kernel_launch(void* const* d_in, const int* in_sizes, int n_in,
                              void* d_out, int out_size, void* d_ws, size_t ws_size,
                              hipStream_t stream) {
  const float* hidden  = (const float*)d_in[0];
  const float* Wq      = (const float*)d_in[1];
  const float* Wk      = (const float*)d_in[2];
  const float* Wv      = (const float*)d_in[3];
  const float* Wo      = (const float*)d_in[4];
  const float* bo      = (const float*)d_in[5];
  const float* Wq_i2v  = (const float*)d_in[6];
  const float* Wo_i2v  = (const float*)d_in[7];
  const float* bo_i2v  = (const float*)d_in[8];
  float* out = (float*)d_out;

  const size_t SZ  = (size_t)MROWS * CDIM;    // 2,621,440
  const size_t SZP = (size_t)MROWS * QPAD;    // 4,194,304
  short* Ah  = (short*)d_ws;                  // [8192][320] split hidden (hi)
  short* Al  = Ah + SZ;                       // [8192][320] (lo)
  short* AOh = Ah;                            // attn out [8192][640] — aliases Ah/Al (dead after G1)
  short* Qp  = Al + SZ;                       // [8192][512] padded
  short* Kp  = Qp + SZP;                      // [8192][512] padded
  short* Qip = Kp + SZP;                      // [8192][512] padded
  short* Vt  = Qip + SZP;                     // [328][8192] (rows 320..327 slack)
  short* WTh = Vt + (size_t)328 * MROWS;
  short* WTl = WTh + 409600;
  short* WFh = WTl + 409600;                  // [320][640] transposed [Wo; Wc]
  short* WFl = WFh + 204800;
  float* Wc  = (float*)(WFl + 204800);
  float* bc  = Wc + 102400;

  const float qscale = 0.15811388300841898f;  // 1/sqrt(40), folded into Q/Q_i2v

  // P1: Wc = Wo_i2v @ Wo
  wc_kernel<<<dim3(5, 5), 256, 0, stream>>>(Wo_i2v, Wo, Wc);

  // P2: split/transpose/zero-pad
  pack_kernel<<<dim3(264), 256, 0, stream>>>(
      hidden, Wq, Wk, Wv, Wq_i2v, Wo, Wc, bo, bo_i2v,
      Ah, Al, WTh, WTl, WFh, WFl, bc, Qp, Kp, Qip, qscale);

  // G1: projections (3-term split MFMA) -> padded Q/K/Qi + V^T
  mfma_gemm<<<dim3(64, 20), 256, 0, stream>>>(
      Ah, Al, WTh, WTl, 320, 0, Qp, Kp, Vt, Qip, nullptr, nullptr);

  // A: both attentions (base: per-frame KV; i2v: frame-0 KV) -> AOh [8192][640]
  attn_kernel<<<dim3(8, 8, 16), 256, 0, stream>>>(Qp, Qip, Kp, Vt, AOh);

  // G2: out = [base|i2v] @ [Wo; Wo_i2v@Wo] + (bo + bo_i2v@Wo), scattered (2-term)
  mfma_gemm<<<dim3(64, 5), 256, 0, stream>>>(
      AOh, nullptr, WFh, WFl, 640, 1, nullptr, nullptr, nullptr, nullptr, out, bc);
}

// Round 12
// 200.908 us; speedup vs baseline: 1.1309x; 1.0438x over previous
//
#include <hip/hip_runtime.h>
#include <hip/hip_bf16.h>

// Problem constants: b=1, n=4 views, f=8 frames, l=256, C=320, H=8, d=40
#define MROWS 8192   // (b*f) * (n*l)
#define CDIM  320
#define QPAD  512    // padded row stride for Q/K/Qi: 8 heads x 64 (cols 40..63 zero)

typedef __attribute__((ext_vector_type(8))) short bf16x8;
typedef __attribute__((ext_vector_type(4))) float f32x4;

__device__ __forceinline__ unsigned bfbits(float x) {  // round-half-up bf16 bits (hi16)
  union { float f; unsigned u; } a; a.f = x;
  return a.u + 0x8000u;
}
__device__ __forceinline__ void splitbf(float x, short& hi, short& lo) {
  unsigned hu = bfbits(x) & 0xffff0000u;
  union { unsigned u; float f; } h; h.u = hu;
  hi = (short)(hu >> 16);
  lo = (short)(bfbits(x - h.f) >> 16);
}
// HW packed f32->bf16 (RNE) via official intrinsic -> v_cvt_pk_bf16_f32
__device__ __forceinline__ unsigned pk_bf16(float a, float b) {
  union { __hip_bfloat162 h2; unsigned u; } cv;
  cv.h2 = __float22bfloat162_rn(float2{a, b});
  return cv.u;   // a in low 16, b in high 16
}

// async global->LDS DMA, 16B/lane; LDS dest = wave-uniform base + lane*16
__device__ __forceinline__ void cp16_g2l(const void* g, void* l) {
  __builtin_amdgcn_global_load_lds(
      (const __attribute__((address_space(1))) void*)g,
      (__attribute__((address_space(3))) void*)l, 16, 0, 0);
}

// rearrange '(b n f) l c -> (b f) (n l) c' row map (involution)
__device__ __forceinline__ int swizzle_row(int r) {
  int ff = r >> 10;
  int t  = r & 1023;
  int nn = t >> 8;
  int ll = t & 255;
  return nn * 2048 + ff * 256 + ll;
}

// ---------------------------------------------------------------------------
// P1: Wc = Wo_i2v @ Wo, fp32, 64x64 tiles, grid (5,5). Tiny (65 MFLOP).
// ---------------------------------------------------------------------------
__global__ __launch_bounds__(256) void wc_kernel(
    const float* __restrict__ Woi, const float* __restrict__ Wo,
    float* __restrict__ Wc)
{
  const int r0 = blockIdx.x * 64, c0 = blockIdx.y * 64;
  __shared__ float As[64][36];
  __shared__ float Bs[32][68];
  const int tid = threadIdx.x, tx = tid & 15, ty = tid >> 4;
  float acc[4][4] = {};

  const int ra = tid >> 3, kq = (tid & 7) * 4;
  const int kb = tid >> 4, cq = (tid & 15) * 4;

  for (int k0 = 0; k0 < 320; k0 += 32) {
    float4 a1 = *(const float4*)(Woi + (size_t)(r0 + ra) * 320 + k0 + kq);
    float4 a2 = *(const float4*)(Woi + (size_t)(r0 + ra + 32) * 320 + k0 + kq);
    float4 b1 = *(const float4*)(Wo + (size_t)(k0 + kb) * 320 + c0 + cq);
    float4 b2 = *(const float4*)(Wo + (size_t)(k0 + kb + 16) * 320 + c0 + cq);
    __syncthreads();
    *(float4*)&As[ra][kq] = a1;
    *(float4*)&As[ra + 32][kq] = a2;
    *(float4*)&Bs[kb][cq] = b1;
    *(float4*)&Bs[kb + 16][cq] = b2;
    __syncthreads();
    #pragma unroll
    for (int kk = 0; kk < 32; ++kk) {
      float4 bv = *(const float4*)&Bs[kk][tx * 4];
      #pragma unroll
      for (int i = 0; i < 4; ++i) {
        float a = As[ty * 4 + i][kk];
        acc[i][0] = fmaf(a, bv.x, acc[i][0]);
        acc[i][1] = fmaf(a, bv.y, acc[i][1]);
        acc[i][2] = fmaf(a, bv.z, acc[i][2]);
        acc[i][3] = fmaf(a, bv.w, acc[i][3]);
      }
    }
  }
  #pragma unroll
  for (int i = 0; i < 4; ++i) {
    float4 v = make_float4(acc[i][0], acc[i][1], acc[i][2], acc[i][3]);
    *(float4*)(Wc + (size_t)(r0 + ty * 4 + i) * 320 + c0 + tx * 4) = v;
  }
}

// ---------------------------------------------------------------------------
// P2: pack/split/zero everything (identical to round 10).
// ---------------------------------------------------------------------------
__global__ __launch_bounds__(256) void pack_kernel(
    const float* __restrict__ hidden,
    const float* __restrict__ Wq, const float* __restrict__ Wk,
    const float* __restrict__ Wv, const float* __restrict__ Wqi,
    const float* __restrict__ Wo, const float* __restrict__ Wc,
    const float* __restrict__ bo, const float* __restrict__ boi,
    short* __restrict__ Ah, short* __restrict__ Al,
    short* __restrict__ WTh, short* __restrict__ WTl,
    short* __restrict__ WFh, short* __restrict__ WFl,
    float* __restrict__ bc,
    short* __restrict__ Qp, short* __restrict__ Kp, short* __restrict__ Qip,
    float qscale)
{
  const int b = blockIdx.x, tid = threadIdx.x;
  if (b < 64) {
    const int r0 = b * 128;
    for (int e = tid; e < 128 * 80; e += 256) {
      int r = e / 80, cq = (e % 80) * 4;
      float4 x = *(const float4*)(hidden + (size_t)swizzle_row(r0 + r) * 320 + cq);
      union { ushort4 v; short s[4]; } h, l;
      splitbf(x.x, h.s[0], l.s[0]); splitbf(x.y, h.s[1], l.s[1]);
      splitbf(x.z, h.s[2], l.s[2]); splitbf(x.w, h.s[3], l.s[3]);
      *(ushort4*)&Ah[(size_t)(r0 + r) * 320 + cq] = h.v;
      *(ushort4*)&Al[(size_t)(r0 + r) * 320 + cq] = l.v;
    }
  } else if (b < 128) {
    const int t2 = b - 64, wi = t2 >> 4, seg = t2 & 15;
    const float* W = wi == 0 ? Wq : wi == 1 ? Wk : wi == 2 ? Wv : Wqi;
    const float s = (wi == 0 || wi == 3) ? qscale : 1.0f;
    short* th = WTh + (size_t)wi * 320 * 320;
    short* tl = WTl + (size_t)wi * 320 * 320;
    for (int e = tid; e < 20 * 320; e += 256) {
      int n = seg * 20 + e / 320, k = e % 320;
      short hi, lo;
      splitbf(W[(size_t)k * 320 + n] * s, hi, lo);
      th[(size_t)n * 320 + k] = hi;
      tl[(size_t)n * 320 + k] = lo;
    }
  } else if (b < 160) {
    const int t2 = b - 128;
    for (int e = tid; e < 10 * 640; e += 256) {
      int n = t2 * 10 + e / 640, k = e % 640;
      float x = (k < 320) ? Wo[(size_t)k * 320 + n] : Wc[(size_t)(k - 320) * 320 + n];
      short hi, lo;
      splitbf(x, hi, lo);
      WFh[(size_t)n * 640 + k] = hi;
      WFl[(size_t)n * 640 + k] = lo;
    }
  } else if (b < 168) {
    const int n = (b - 160) * 40 + tid;
    if (tid < 40) {
      float s = bo[n];
      for (int j = 0; j < 320; ++j) s = fmaf(boi[j], Wo[(size_t)j * 320 + n], s);
      bc[n] = s;
    }
  } else {
    const int bz = b - 168, buf = bz >> 5, seg = bz & 31;
    short* P = buf == 0 ? Qp : buf == 1 ? Kp : Qip;
    const uint4 z = make_uint4(0, 0, 0, 0);
    for (int e = tid; e < 256 * 24; e += 256) {
      int row = (seg << 8) + (e / 24);
      int cc = e % 24, h = cc / 3, c3 = cc % 3;
      *(uint4*)&P[(size_t)row * QPAD + h * 64 + 40 + c3 * 8] = z;
    }
  }
}

// ---------------------------------------------------------------------------
// Split-bf16 MFMA GEMM with global_load_lds(16B) staging (identical to r10).
// ---------------------------------------------------------------------------
__global__ __launch_bounds__(256, 3) void mfma_gemm(
    const short* __restrict__ Ah, const short* __restrict__ Al,
    const short* __restrict__ BTh, const short* __restrict__ BTl,
    int K, int mode,
    short* __restrict__ Qp, short* __restrict__ Kp,
    short* __restrict__ Vt, short* __restrict__ Qip,
    float* __restrict__ Of, const float* __restrict__ bias)
{
  const int tid  = threadIdx.x;
  const int wave = tid >> 6;
  const int lane = tid & 63;
  const int quad = lane >> 4;
  const int l16  = lane & 15;
  const int row0 = blockIdx.x * 128;

  const short *bth, *btl;
  int nbase, wi = 0;
  if (mode == 0) {
    const int ct = blockIdx.y;
    wi = ct / 5;
    bth = BTh + (size_t)wi * 320 * 320;
    btl = BTl + (size_t)wi * 320 * 320;
    nbase = (ct % 5) * 64;
  } else {
    bth = BTh; btl = BTl;
    nbase = blockIdx.y * 64;
  }

  __shared__ short Ash[128][32], Asl[128][32];
  __shared__ short Bsh[64][32],  Bsl[64][32];

  f32x4 acc[2][4];
  #pragma unroll
  for (int mt = 0; mt < 2; ++mt)
    #pragma unroll
    for (int nt = 0; nt < 4; ++nt) acc[mt][nt] = (f32x4){0.f, 0.f, 0.f, 0.f};

  const int lr = lane >> 2, lc = (lane & 3) * 8;
  const short* gah = Ah + (size_t)(row0 + wave * 16 + lr) * K + lc;
  const short* gal = Al ? Al + (size_t)(row0 + wave * 16 + lr) * K + lc : nullptr;
  const short* gbh = bth + (size_t)(nbase + wave * 16 + lr) * K + lc;
  const short* gbl = btl + (size_t)(nbase + wave * 16 + lr) * K + lc;
  short* lah1 = &Ash[wave * 16][0];
  short* lah2 = &Ash[64 + wave * 16][0];
  short* lal1 = &Asl[wave * 16][0];
  short* lal2 = &Asl[64 + wave * 16][0];
  short* lbh  = &Bsh[wave * 16][0];
  short* lbl  = &Bsl[wave * 16][0];

  for (int k0 = 0; k0 < K; k0 += 32) {
    __syncthreads();
    cp16_g2l(gah + k0, lah1);
    cp16_g2l(gah + (size_t)64 * K + k0, lah2);
    if (Al) {
      cp16_g2l(gal + k0, lal1);
      cp16_g2l(gal + (size_t)64 * K + k0, lal2);
    }
    cp16_g2l(gbh + k0, lbh);
    cp16_g2l(gbl + k0, lbl);
    __syncthreads();

    bf16x8 afh[2], afl[2], bfh[4], bfl[4];
    #pragma unroll
    for (int mt = 0; mt < 2; ++mt) {
      afh[mt] = *(const bf16x8*)&Ash[wave * 32 + mt * 16 + l16][quad * 8];
      if (Al) afl[mt] = *(const bf16x8*)&Asl[wave * 32 + mt * 16 + l16][quad * 8];
    }
    #pragma unroll
    for (int nt = 0; nt < 4; ++nt) {
      bfh[nt] = *(const bf16x8*)&Bsh[nt * 16 + l16][quad * 8];
      bfl[nt] = *(const bf16x8*)&Bsl[nt * 16 + l16][quad * 8];
    }
    #pragma unroll
    for (int mt = 0; mt < 2; ++mt)
      #pragma unroll
      for (int nt = 0; nt < 4; ++nt) {
        acc[mt][nt] = __builtin_amdgcn_mfma_f32_16x16x32_bf16(afh[mt], bfh[nt], acc[mt][nt], 0, 0, 0);
        acc[mt][nt] = __builtin_amdgcn_mfma_f32_16x16x32_bf16(afh[mt], bfl[nt], acc[mt][nt], 0, 0, 0);
        if (Al)
          acc[mt][nt] = __builtin_amdgcn_mfma_f32_16x16x32_bf16(afl[mt], bfh[nt], acc[mt][nt], 0, 0, 0);
      }
  }

  if (mode == 0) {
    if (wi == 2) {
      #pragma unroll
      for (int mt = 0; mt < 2; ++mt)
        #pragma unroll
        for (int nt = 0; nt < 4; ++nt) {
          const int col  = nbase + nt * 16 + l16;
          const int rowb = row0 + wave * 32 + mt * 16 + quad * 4;
          union { ushort4 v; short s[4]; } pk;
          #pragma unroll
          for (int r = 0; r < 4; ++r) pk.s[r] = (short)(bfbits(acc[mt][nt][r]) >> 16);
          *(ushort4*)&Vt[(size_t)col * MROWS + rowb] = pk.v;
        }
    } else {
      short* Op = wi == 0 ? Qp : wi == 1 ? Kp : Qip;
      #pragma unroll
      for (int mt = 0; mt < 2; ++mt)
        #pragma unroll
        for (int nt = 0; nt < 4; ++nt) {
          const int col  = nbase + nt * 16 + l16;
          const int h    = col / 40;
          const int pcol = h * 64 + (col - h * 40);
          const int rowb = row0 + wave * 32 + mt * 16 + quad * 4;
          #pragma unroll
          for (int r = 0; r < 4; ++r)
            Op[(size_t)(rowb + r) * QPAD + pcol] = (short)(bfbits(acc[mt][nt][r]) >> 16);
        }
    }
  } else {
    #pragma unroll
    for (int mt = 0; mt < 2; ++mt)
      #pragma unroll
      for (int nt = 0; nt < 4; ++nt) {
        const int col  = nbase + nt * 16 + l16;
        const int rowb = row0 + wave * 32 + mt * 16 + quad * 4;
        const float bb = bias[col];
        #pragma unroll
        for (int r = 0; r < 4; ++r)
          Of[(size_t)swizzle_row(rowb + r) * CDIM + col] = acc[mt][nt][r] + bb;
      }
  }
}

// ---------------------------------------------------------------------------
// Flash attention, bf16 MFMA. Round-10 structure (DMA + XOR swizzle, 0 bank
// conflicts) with three VALU cuts:
//  - base-2 softmax: log2e folded into Q-proj scale,
//    p = __builtin_amdgcn_exp2f(s) -> v_exp_f32 (compiler-managed hazards)
//  - P pack via __float22bfloat162_rn (v_cvt_pk_bf16_f32, 1 op per pair)
//  - denominator via MFMA ones-column: Vt row 40 = 1.0 -> P@V t=2 col 40
//    (lane l16==8) accumulates sum(P); no lsum adds, no epilogue reduce.
// grid = (8 qblk, 8 heads, 16 = bf + 8*variant).
// ---------------------------------------------------------------------------
__global__ __launch_bounds__(256, 4) void attn_kernel(
    const short* __restrict__ Qp, const short* __restrict__ Qip,
    const short* __restrict__ Kp, const short* __restrict__ Vtg,
    short* __restrict__ AOh)
{
  const int qblk = blockIdx.x;   // 0..7 (128 q-rows per block)
  const int hh   = blockIdx.y;   // 0..7
  const int zz   = blockIdx.z;   // 0..15
  const int var  = zz >> 3;
  const int bf   = zz & 7;
  const int tid  = threadIdx.x;
  const int wave = tid >> 6;
  const int lane = tid & 63;
  const int quad = lane >> 4;
  const int l16  = lane & 15;

  const short* Q = var ? Qip : Qp;
  const int kvbase = var ? 0 : (bf << 10);
  const int coff = var * 320 + hh * 40;

  __shared__ short Ks[64][64];    // [key][kd], cols 40..63 zero (from Kp pad)
  __shared__ short Vt[48][64];    // [dcol][key]; row 40 = ones, 41..47 zero
  __shared__ short Ps[4][16][68]; // per-wave P buffer (one q-tile at a time)

  // init pad rows once (DMA never writes rows 40..47): row 40 = 1.0 bf16
  if (tid < 64) {
    const int pr = tid >> 3;
    uint4 fill = (pr == 0) ? make_uint4(0x3F803F80u, 0x3F803F80u, 0x3F803F80u, 0x3F803F80u)
                           : make_uint4(0, 0, 0, 0);
    *(uint4*)&Vt[40 + pr][(tid & 7) * 8] = fill;
  }

  // Q B-fragments: 2 q-tiles of 16 rows; n = l16 = q-row, k = quad*8+j
  bf16x8 qf0[2], qf1[2];
  #pragma unroll
  for (int qt = 0; qt < 2; ++qt) {
    const short* qp = Q + (size_t)((bf << 10) + (qblk << 7) + (wave << 5) + (qt << 4) + l16) * QPAD + hh * 64;
    qf0[qt] = *(const bf16x8*)(qp + quad * 8);
    qf1[qt] = *(const bf16x8*)(qp + 32 + quad * 8);
  }

  f32x4 acc[2][3];
  #pragma unroll
  for (int qt = 0; qt < 2; ++qt)
    #pragma unroll
    for (int t = 0; t < 3; ++t) acc[qt][t] = (f32x4){0.f, 0.f, 0.f, 0.f};

  const short* Kb = Kp + (size_t)kvbase * QPAD + hh * 64;
  const short* Vb = Vtg + (size_t)(hh * 40) * MROWS + kvbase;

  // DMA lane geometry: row = base + lane/8, LDS chunk = lane%8,
  // global chunk = (lane%8) ^ ((lane/8)&7)   (XOR swizzle on global side)
  const int lrow = lane >> 3;
  const int gch  = ((lane & 7) ^ (lrow & 7)) * 8;
  const int sw   = l16 & 7;   // row&7 for fragment-read de-swizzle

  for (int s0 = 0; s0 < 1024; s0 += 64) {
    __syncthreads();                 // previous step fully consumed
    #pragma unroll
    for (int j = 0; j < 4; ++j) {
      const int u = j * 4 + wave;    // wave-uniform unit id
      if (u < 8) {                   // K rows u*8 .. u*8+7
        cp16_g2l(Kb + (size_t)(s0 + u * 8 + lrow) * QPAD + gch, &Ks[u * 8][0]);
      } else if (u < 13) {           // V d-rows (u-8)*8 .. (rows 0..39 only)
        cp16_g2l(Vb + (size_t)((u - 8) * 8 + lrow) * MROWS + s0 + gch, &Vt[(u - 8) * 8][0]);
      }
    }
    __syncthreads();                 // vmcnt drained + visible

    // V B-fragments (shared across q-tiles), de-swizzled chunk index
    bf16x8 vf[2][3];
    #pragma unroll
    for (int kh = 0; kh < 2; ++kh)
      #pragma unroll
      for (int t = 0; t < 3; ++t)
        vf[kh][t] = *(const bf16x8*)&Vt[t * 16 + l16][((kh * 4 + quad) ^ sw) * 8];

    #pragma unroll
    for (int qt = 0; qt < 2; ++qt) {
      // ---- QK^T + 2^s + pack, per kt (K frags transient) ----
      #pragma unroll
      for (int kt = 0; kt < 4; ++kt) {
        const short* kr = &Ks[kt * 16 + l16][0];
        bf16x8 kb0 = *(const bf16x8*)(kr + (quad ^ sw) * 8);
        bf16x8 kb1 = *(const bf16x8*)(kr + ((quad + 4) ^ sw) * 8);
        f32x4 st = (f32x4){0.f, 0.f, 0.f, 0.f};
        st = __builtin_amdgcn_mfma_f32_16x16x32_bf16(kb0, qf0[qt], st, 0, 0, 0);
        st = __builtin_amdgcn_mfma_f32_16x16x32_bf16(kb1, qf1[qt], st, 0, 0, 0);
        float p0 = __builtin_amdgcn_exp2f(st[0]);
        float p1 = __builtin_amdgcn_exp2f(st[1]);
        float p2 = __builtin_amdgcn_exp2f(st[2]);
        float p3 = __builtin_amdgcn_exp2f(st[3]);
        uint2 pk;
        pk.x = pk_bf16(p0, p1);
        pk.y = pk_bf16(p2, p3);
        // keys kt*16 + quad*4 + {0..3} for q-row l16 (stride-68 rows)
        *(uint2*)&Ps[wave][l16][kt * 16 + quad * 4] = pk;
      }

      // wave-internal LDS RAW (cross-lane): drain before reading P
      asm volatile("s_waitcnt lgkmcnt(0)" ::: "memory");

      // ---- P @ V (t=2 col 40 accumulates sum(P) via ones-row) ----
      bf16x8 pa0 = *(const bf16x8*)&Ps[wave][l16][quad * 8];
      bf16x8 pa1 = *(const bf16x8*)&Ps[wave][l16][32 + quad * 8];
      #pragma unroll
      for (int t = 0; t < 3; ++t) {
        acc[qt][t] = __builtin_amdgcn_mfma_f32_16x16x32_bf16(pa0, vf[0][t], acc[qt][t], 0, 0, 0);
        acc[qt][t] = __builtin_amdgcn_mfma_f32_16x16x32_bf16(pa1, vf[1][t], acc[qt][t], 0, 0, 0);
      }
      // next qt's Ps writes are safe (DS ops in-order within a wave)
    }
  }

  // ---- epilogue: denom = acc[qt][2][r] at lane l16==8 (col 40) ----
  #pragma unroll
  for (int qt = 0; qt < 2; ++qt) {
    float invr[4];
    #pragma unroll
    for (int r = 0; r < 4; ++r) {
      float d = __shfl(acc[qt][2][r], quad * 16 + 8, 64);  // col-40 lane of this quad
      invr[r] = 1.f / d;
    }

    const int baserow = (bf << 10) + (qblk << 7) + (wave << 5) + (qt << 4) + quad * 4;
    #pragma unroll
    for (int t = 0; t < 3; ++t) {
      int dcol = t * 16 + l16;
      if (dcol < 40) {
        short* op = AOh + (size_t)baserow * 640 + coff + dcol;
        #pragma unroll
        for (int r = 0; r < 4; ++r)
          op[(size_t)r * 640] = (short)(bfbits(acc[qt][t][r] * invr[r]) >> 16);
      }
    }
  }
}

// ---------------------------------------------------------------------------
extern "C" void kernel_launch(void* const* d_in, const int* in_sizes, int n_in,
                              void* d_out, int out_size, void* d_ws, size_t ws_size,
                              hipStream_t stream) {
  const float* hidden  = (const float*)d_in[0];
  const float* Wq      = (const float*)d_in[1];
  const float* Wk      = (const float*)d_in[2];
  const float* Wv      = (const float*)d_in[3];
  const float* Wo      = (const float*)d_in[4];
  const float* bo      = (const float*)d_in[5];
  const float* Wq_i2v  = (const float*)d_in[6];
  const float* Wo_i2v  = (const float*)d_in[7];
  const float* bo_i2v  = (const float*)d_in[8];
  float* out = (float*)d_out;

  const size_t SZ  = (size_t)MROWS * CDIM;    // 2,621,440
  const size_t SZP = (size_t)MROWS * QPAD;    // 4,194,304
  short* Ah  = (short*)d_ws;                  // [8192][320] split hidden (hi)
  short* Al  = Ah + SZ;                       // [8192][320] (lo)
  short* AOh = Ah;                            // attn out [8192][640] — aliases Ah/Al (dead after G1)
  short* Qp  = Al + SZ;                       // [8192][512] padded
  short* Kp  = Qp + SZP;                      // [8192][512] padded
  short* Qip = Kp + SZP;                      // [8192][512] padded
  short* Vt  = Qip + SZP;                     // [328][8192] (rows 320..327 slack)
  short* WTh = Vt + (size_t)328 * MROWS;
  short* WTl = WTh + 409600;
  short* WFh = WTl + 409600;                  // [320][640] transposed [Wo; Wc]
  short* WFl = WFh + 204800;
  float* Wc  = (float*)(WFl + 204800);
  float* bc  = Wc + 102400;

  // (1/sqrt(40)) * log2(e): QK^T scores come out in base-2 scale for exp2
  const float qscale = 0.22811011717177393f;

  // P1: Wc = Wo_i2v @ Wo
  wc_kernel<<<dim3(5, 5), 256, 0, stream>>>(Wo_i2v, Wo, Wc);

  // P2: split/transpose/zero-pad
  pack_kernel<<<dim3(264), 256, 0, stream>>>(
      hidden, Wq, Wk, Wv, Wq_i2v, Wo, Wc, bo, bo_i2v,
      Ah, Al, WTh, WTl, WFh, WFl, bc, Qp, Kp, Qip, qscale);

  // G1: projections (3-term split MFMA) -> padded Q/K/Qi + V^T
  mfma_gemm<<<dim3(64, 20), 256, 0, stream>>>(
      Ah, Al, WTh, WTl, 320, 0, Qp, Kp, Vt, Qip, nullptr, nullptr);

  // A: both attentions (base: per-frame KV; i2v: frame-0 KV) -> AOh [8192][640]
  attn_kernel<<<dim3(8, 8, 16), 256, 0, stream>>>(Qp, Qip, Kp, Vt, AOh);

  // G2: out = [base|i2v] @ [Wo; Wo_i2v@Wo] + (bo + bo_i2v@Wo), scattered (2-term)
  mfma_gemm<<<dim3(64, 5), 256, 0, stream>>>(
      AOh, nullptr, WFh, WFl, 640, 1, nullptr, nullptr, nullptr, nullptr, out, bc);
}